// Round 6
// baseline (403.983 us; speedup 1.0000x reference)
//
#include <hip/hip_runtime.h>
#include <stdint.h>

#define NN 50000
#define NE 800000
#define NBIN 196   // dst buckets of 256 nodes (dst >> 8)
#define ABLK 98    // blocks in hist/bin passes
#define EPB 8164   // edges per block: 98*8164 >= NE
#define BCAP 6144  // per-bucket LDS capacity (avg 4096, sigma ~64)

typedef __attribute__((ext_vector_type(8))) short short8;
typedef __attribute__((ext_vector_type(4))) float floatx4;

__device__ __forceinline__ uint16_t f2bf(float f){
  union { float f; uint32_t u; } c; c.f = f;
  uint32_t u = c.u + 0x7FFFu + ((c.u >> 16) & 1u);
  return (uint16_t)(u >> 16);
}
__device__ __forceinline__ float bflo(uint32_t v){
  union { uint32_t u; float f; } c; c.u = v << 16; return c.f;
}
__device__ __forceinline__ float bfhi(uint32_t v){
  union { uint32_t u; float f; } c; c.u = v & 0xFFFF0000u; return c.f;
}
__device__ __forceinline__ float bfs(uint16_t v){
  union { uint32_t u; float f; } c; c.u = ((uint32_t)v) << 16; return c.f;
}

// ---------------- fused preprocessing: cvt + hist + weight packs ----------------
#define B_CVT 6250   // NN*128/4 / 256
#define B_HIST ABLK
#define B_PIN 64
#define B_P0  128
#define B_P1  128
#define B_P2  64

__device__ __forceinline__ void pack_one(int idx, const float* __restrict__ wl,
                                         const float* __restrict__ wr,
                                         uint16_t* __restrict__ bp,
                                         int ncolL, int ncolR, int NT){
  int j = idx & 7, lane = (idx >> 3) & 63, rest = idx >> 9;
  int nt = rest % NT, kt = rest / NT;
  int k = kt * 32 + ((lane >> 4) << 3) + j;
  int n = nt * 16 + (lane & 15);
  float v = (n < ncolL) ? wl[k * ncolL + n] : wr[k * ncolR + (n - ncolL)];
  bp[idx] = f2bf(v);
}

__global__ __launch_bounds__(256) void k_prep(const float* __restrict__ x, uint2* __restrict__ xb,
                                              const int* __restrict__ ei, int* __restrict__ histG,
                                              const float* __restrict__ w_in,
                                              const float* __restrict__ w_l0, const float* __restrict__ w_r0,
                                              const float* __restrict__ w_l1, const float* __restrict__ w_r1,
                                              const float* __restrict__ w_l2, const float* __restrict__ w_r2,
                                              uint16_t* __restrict__ bpIn, uint16_t* __restrict__ bp0,
                                              uint16_t* __restrict__ bp1, uint16_t* __restrict__ bp2){
  __shared__ int hsh[NBIN];
  int b = blockIdx.x;
  if (b < B_CVT){
    int i = b * 256 + threadIdx.x;
    if (i < NN * 128 / 4){
      float4 v = ((const float4*)x)[i];
      uint32_t lo = (uint32_t)f2bf(v.x) | ((uint32_t)f2bf(v.y) << 16);
      uint32_t hi = (uint32_t)f2bf(v.z) | ((uint32_t)f2bf(v.w) << 16);
      xb[i] = make_uint2(lo, hi);
    }
    return;
  }
  b -= B_CVT;
  if (b < B_HIST){
    for (int i = threadIdx.x; i < NBIN; i += 256) hsh[i] = 0;
    __syncthreads();
    int base = b * EPB;
    for (int k = threadIdx.x; k < EPB; k += 256){
      int e = base + k;
      if (e < NE) atomicAdd(&hsh[ei[NE + e] >> 8], 1);
    }
    __syncthreads();
    for (int i = threadIdx.x; i < NBIN; i += 256) histG[i * ABLK + b] = hsh[i];
    return;
  }
  b -= B_HIST;
  if (b < B_PIN){ pack_one(b * 256 + threadIdx.x, w_in, w_in, bpIn, 128, 0, 8); return; }
  b -= B_PIN;
  if (b < B_P0){ pack_one(b * 256 + threadIdx.x, w_l0, w_r0, bp0, 128, 128, 16); return; }
  b -= B_P0;
  if (b < B_P1){ pack_one(b * 256 + threadIdx.x, w_l1, w_r1, bp1, 128, 128, 16); return; }
  b -= B_P1;
  pack_one(b * 256 + threadIdx.x, w_l2, w_r2, bp2, 64, 64, 8);
}

// ---------------- pass A2: scan (bin-major over blocks) + bin bases ----------------
__global__ __launch_bounds__(256) void k_scanG(int* __restrict__ histG, int* __restrict__ binStart){
  __shared__ int s[256];
  int t = threadIdx.x;
  int tot = 0;
  if (t < NBIN){
    for (int b = 0; b < ABLK; ++b){
      int v = histG[t * ABLK + b];
      histG[t * ABLK + b] = tot;
      tot += v;
    }
  }
  s[t] = (t < NBIN) ? tot : 0;
  __syncthreads();
  #pragma unroll
  for (int off = 1; off < 256; off <<= 1){
    int u = (t >= off) ? s[t - off] : 0;
    __syncthreads();
    s[t] += u;
    __syncthreads();
  }
  int excl = s[t] - ((t < NBIN) ? tot : 0);
  if (t < NBIN){
    binStart[t] = excl;
    for (int b = 0; b < ABLK; ++b) histG[t * ABLK + b] += excl;
  }
  if (t == 0) binStart[NBIN] = NE;
}

// ---------------- pass A3: LDS bin-sort, contiguous-run writes ----------------
__global__ __launch_bounds__(256) void k_bin(const int* __restrict__ ei, const int* __restrict__ histG,
                                             uint32_t* __restrict__ pairs){
  __shared__ int h[NBIN], loc[NBIN], cur[NBIN], gof[NBIN];
  __shared__ int sc[256];
  __shared__ uint32_t st[EPB];
  int t = threadIdx.x;
  int base = blockIdx.x * EPB;
  for (int i = t; i < NBIN; i += 256) h[i] = 0;
  __syncthreads();
  for (int k = t; k < EPB; k += 256){
    int e = base + k;
    if (e < NE) atomicAdd(&h[ei[NE + e] >> 8], 1);
  }
  __syncthreads();
  int cv = (t < NBIN) ? h[t] : 0;
  sc[t] = cv;
  __syncthreads();
  #pragma unroll
  for (int off = 1; off < 256; off <<= 1){
    int u = (t >= off) ? sc[t - off] : 0;
    __syncthreads();
    sc[t] += u;
    __syncthreads();
  }
  if (t < NBIN){
    int excl = sc[t] - cv;
    loc[t] = excl;
    cur[t] = excl;
    gof[t] = histG[t * ABLK + blockIdx.x];
  }
  __syncthreads();
  for (int k = t; k < EPB; k += 256){
    int e = base + k;
    if (e < NE){
      int d = ei[NE + e];
      int s0 = ei[e];
      int pos = atomicAdd(&cur[d >> 8], 1);
      st[pos] = (uint32_t)s0 | ((uint32_t)d << 16);
    }
  }
  __syncthreads();
  int cnt = min(EPB, NE - base);
  for (int k = t; k < cnt; k += 256){
    uint32_t v = st[k];
    int bin = (int)(v >> 24);
    pairs[gof[bin] + (k - loc[bin])] = v;
  }
}

// ---------------- pass B: per-bucket counting sort -> rowp + colx(u16, src-sorted) ----------------
__global__ __launch_bounds__(256) void k_csr(const uint32_t* __restrict__ pairs, const int* __restrict__ binStart,
                                             int* __restrict__ rowp, uint16_t* __restrict__ colx){
  __shared__ uint32_t pl[BCAP];
  __shared__ uint16_t stg[BCAP];
  __shared__ int h[256], sc[256];
  int i = blockIdx.x, t = threadIdx.x;
  int p0 = binStart[i], p1 = binStart[i + 1];
  int cnt = min(p1 - p0, BCAP);
  for (int k = t; k < cnt; k += 256) pl[k] = pairs[p0 + k];
  h[t] = 0;
  __syncthreads();
  for (int k = t; k < cnt; k += 256) atomicAdd(&h[(pl[k] >> 16) & 255], 1);
  __syncthreads();
  int cv = h[t];
  sc[t] = cv;
  __syncthreads();
  #pragma unroll
  for (int off = 1; off < 256; off <<= 1){
    int u = (t >= off) ? sc[t - off] : 0;
    __syncthreads();
    sc[t] += u;
    __syncthreads();
  }
  int excl = sc[t] - cv;
  int n0 = i << 8;
  int nc = min(256, NN - n0);
  if (t < nc) rowp[n0 + t] = p0 + excl;
  if (i == NBIN - 1 && t == 0) rowp[NN] = NE;
  h[t] = excl;   // becomes cursor
  __syncthreads();
  for (int k = t; k < cnt; k += 256){
    uint32_t v = pl[k];
    int pos = atomicAdd(&h[(v >> 16) & 255], 1);
    stg[pos] = (uint16_t)(v & 0xFFFFu);
  }
  __syncthreads();
  // per-node insertion sort by src (gather locality; sum order is irrelevant)
  {
    int st0 = excl, cnt0 = cv;
    for (int a = st0 + 1; a < st0 + cnt0; ++a){
      uint16_t key = stg[a];
      int b2 = a - 1;
      while (b2 >= st0 && stg[b2] > key){ stg[b2 + 1] = stg[b2]; --b2; }
      stg[b2 + 1] = key;
    }
  }
  __syncthreads();
  for (int k = t; k < cnt; k += 256) colx[p0 + k] = stg[k];
}

// ------------- GEMM: A[N,128]bf16 @ Bp[128, NCOL] -> epilogue -------------
// MODE 0: lin_in: h=acc+bias; o0=bf16(relu h); o1=bf16(0.2h)
// MODE 1: conv0 : c<128 -> o0=bf16(acc) [y]; else o1=bf16(acc+bias) [z]
template<int NTW, int MODE>
__global__ __launch_bounds__(256) void k_gemm(const uint16_t* __restrict__ A, const uint16_t* __restrict__ Bp,
                                              const float* __restrict__ bias,
                                              uint16_t* __restrict__ o0, uint16_t* __restrict__ o1){
  const int NTT = 4 * NTW;
  int lane = threadIdx.x & 63;
  int wave = threadIdx.x >> 6;
  short8 bfrag[4][NTW];
  #pragma unroll
  for (int kt = 0; kt < 4; ++kt)
    #pragma unroll
    for (int n = 0; n < NTW; ++n)
      bfrag[kt][n] = *(const short8*)(Bp + (size_t)((kt * NTT + wave * NTW + n) * 64 + lane) * 8);

  int m = lane & 15, quad = lane >> 4;
  const int nrt = NN / 16;
  for (int rt = blockIdx.x; rt < nrt; rt += gridDim.x){
    int r0 = rt * 16;
    const uint16_t* arow = A + (size_t)(r0 + m) * 128 + quad * 8;
    short8 af[4];
    #pragma unroll
    for (int kt = 0; kt < 4; ++kt) af[kt] = *(const short8*)(arow + kt * 32);
    floatx4 acc[NTW];
    #pragma unroll
    for (int n = 0; n < NTW; ++n) acc[n] = (floatx4){0.f, 0.f, 0.f, 0.f};
    #pragma unroll
    for (int kt = 0; kt < 4; ++kt)
      #pragma unroll
      for (int n = 0; n < NTW; ++n)
        acc[n] = __builtin_amdgcn_mfma_f32_16x16x32_bf16(af[kt], bfrag[kt][n], acc[n], 0, 0, 0);

    int rbase = r0 + quad * 4;
    #pragma unroll
    for (int n = 0; n < NTW; ++n){
      int c = (wave * NTW + n) * 16 + m;
      #pragma unroll
      for (int i = 0; i < 4; ++i){
        float v = acc[n][i];
        int row = rbase + i;
        if (MODE == 0){
          float hh = v + bias[c];
          o0[(size_t)row * 128 + c] = f2bf(fmaxf(hh, 0.f));
          o1[(size_t)row * 128 + c] = f2bf(0.2f * hh);
        } else {
          if (c < 128) o0[(size_t)row * 128 + c] = f2bf(v);
          else         o1[(size_t)row * 128 + (c - 128)] = f2bf(v + bias[c - 128]);
        }
      }
    }
  }
}

// ------------- fused: mean-agg + relu + residual -> LDS A-tile -> GEMM -------------
// MODE 1: NCOL=256: c<128 -> o0=bf16 [y]; else o1=bf16(+bias) [z]
// MODE 2: NCOL=128: c<64  -> o0=bf16 [y2]; else o2=fp32(+bias) [z2]
template<int NTW, int MODE>
__global__ __launch_bounds__(256) void k_fused(const uint32_t* __restrict__ yb, const uint32_t* __restrict__ zb,
                                               const uint32_t* __restrict__ resb,
                                               const uint16_t* __restrict__ colx, const int* __restrict__ rowp,
                                               const uint16_t* __restrict__ Bp, const float* __restrict__ bias,
                                               uint16_t* __restrict__ o0, uint16_t* __restrict__ o1,
                                               float* __restrict__ o2){
  const int SP = 68;                  // padded row stride (u32) -> conflict-free-ish
  __shared__ uint32_t ash[16 * SP];
  const int NTT = 4 * NTW;
  int lane = threadIdx.x & 63;
  int wave = threadIdx.x >> 6;

  short8 bfrag[4][NTW];
  #pragma unroll
  for (int kt = 0; kt < 4; ++kt)
    #pragma unroll
    for (int n = 0; n < NTW; ++n)
      bfrag[kt][n] = *(const short8*)(Bp + (size_t)((kt * NTT + wave * NTW + n) * 64 + lane) * 8);

  int r0 = blockIdx.x * 16;
  // ---- aggregation phase: wave w handles nodes r0 + sub*4 + w ----
  #pragma unroll
  for (int sub = 0; sub < 4; ++sub){
    int ni = sub * 4 + wave;
    int g = r0 + ni;
    int e0 = rowp[g], e1 = rowp[g + 1];
    float a0 = 0.f, a1 = 0.f;
    int e = e0;
    for (; e + 8 <= e1; e += 8){
      uint32_t v0 = yb[(size_t)colx[e]     * 64 + lane];
      uint32_t v1 = yb[(size_t)colx[e + 1] * 64 + lane];
      uint32_t v2 = yb[(size_t)colx[e + 2] * 64 + lane];
      uint32_t v3 = yb[(size_t)colx[e + 3] * 64 + lane];
      uint32_t v4 = yb[(size_t)colx[e + 4] * 64 + lane];
      uint32_t v5 = yb[(size_t)colx[e + 5] * 64 + lane];
      uint32_t v6 = yb[(size_t)colx[e + 6] * 64 + lane];
      uint32_t v7 = yb[(size_t)colx[e + 7] * 64 + lane];
      a0 += bflo(v0) + bflo(v1) + bflo(v2) + bflo(v3) + bflo(v4) + bflo(v5) + bflo(v6) + bflo(v7);
      a1 += bfhi(v0) + bfhi(v1) + bfhi(v2) + bfhi(v3) + bfhi(v4) + bfhi(v5) + bfhi(v6) + bfhi(v7);
    }
    for (; e < e1; ++e){
      uint32_t v = yb[(size_t)colx[e] * 64 + lane];
      a0 += bflo(v); a1 += bfhi(v);
    }
    int deg = e1 - e0;
    float inv = deg > 0 ? 1.f / (float)deg : 0.f;
    uint32_t zv = zb[(size_t)g * 64 + lane];
    uint32_t rv = resb[(size_t)g * 64 + lane];
    float v0 = fmaxf(a0 * inv + bflo(zv), 0.f) + bflo(rv);
    float v1 = fmaxf(a1 * inv + bfhi(zv), 0.f) + bfhi(rv);
    ash[ni * SP + lane] = (uint32_t)f2bf(v0) | ((uint32_t)f2bf(v1) << 16);
  }
  __syncthreads();

  // ---- GEMM phase ----
  int m = lane & 15, quad = lane >> 4;
  short8 af[4];
  #pragma unroll
  for (int kt = 0; kt < 4; ++kt)
    af[kt] = *(const short8*)&ash[m * SP + kt * 16 + quad * 4];
  floatx4 acc[NTW];
  #pragma unroll
  for (int n = 0; n < NTW; ++n) acc[n] = (floatx4){0.f, 0.f, 0.f, 0.f};
  #pragma unroll
  for (int kt = 0; kt < 4; ++kt)
    #pragma unroll
    for (int n = 0; n < NTW; ++n)
      acc[n] = __builtin_amdgcn_mfma_f32_16x16x32_bf16(af[kt], bfrag[kt][n], acc[n], 0, 0, 0);

  int rbase = r0 + quad * 4;
  #pragma unroll
  for (int n = 0; n < NTW; ++n){
    int c = (wave * NTW + n) * 16 + m;
    #pragma unroll
    for (int i = 0; i < 4; ++i){
      float v = acc[n][i];
      int row = rbase + i;
      if (MODE == 1){
        if (c < 128) o0[(size_t)row * 128 + c] = f2bf(v);
        else         o1[(size_t)row * 128 + (c - 128)] = f2bf(v + bias[c - 128]);
      } else {
        if (c < 64) o0[(size_t)row * 64 + c] = f2bf(v);
        else        o2[(size_t)row * 64 + (c - 64)] = v + bias[c - 64];
      }
    }
  }
}

// ------------- final aggregation + log_softmax -------------
__global__ __launch_bounds__(256) void agg_out(const uint16_t* __restrict__ yb2, const float* __restrict__ z2,
                                               const uint16_t* __restrict__ colx, const int* __restrict__ rowp,
                                               float* __restrict__ out){
  int wid = blockIdx.x * 4 + (threadIdx.x >> 6);
  if (wid >= NN) return;
  int lane = threadIdx.x & 63;
  int e0 = rowp[wid], e1 = rowp[wid + 1];
  float a = 0.f;
  int e = e0;
  for (; e + 8 <= e1; e += 8){
    a += bfs(yb2[(size_t)colx[e]     * 64 + lane]) + bfs(yb2[(size_t)colx[e + 1] * 64 + lane])
       + bfs(yb2[(size_t)colx[e + 2] * 64 + lane]) + bfs(yb2[(size_t)colx[e + 3] * 64 + lane])
       + bfs(yb2[(size_t)colx[e + 4] * 64 + lane]) + bfs(yb2[(size_t)colx[e + 5] * 64 + lane])
       + bfs(yb2[(size_t)colx[e + 6] * 64 + lane]) + bfs(yb2[(size_t)colx[e + 7] * 64 + lane]);
  }
  for (; e < e1; ++e) a += bfs(yb2[(size_t)colx[e] * 64 + lane]);
  int deg = e1 - e0;
  float inv = deg > 0 ? 1.f / (float)deg : 0.f;
  float v = a * inv + z2[(size_t)wid * 64 + lane];
  float mx = v;
  #pragma unroll
  for (int off = 32; off; off >>= 1) mx = fmaxf(mx, __shfl_xor(mx, off, 64));
  float ex = __expf(v - mx);
  float sm = ex;
  #pragma unroll
  for (int off = 32; off; off >>= 1) sm += __shfl_xor(sm, off, 64);
  out[(size_t)wid * 64 + lane] = (v - mx) - __logf(sm);
}

extern "C" void kernel_launch(void* const* d_in, const int* in_sizes, int n_in,
                              void* d_out, int out_size, void* d_ws, size_t ws_size,
                              hipStream_t stream){
  const float* x    = (const float*)d_in[0];
  const int*   ei   = (const int*)d_in[1];
  const float* w_in = (const float*)d_in[2];
  const float* b_in = (const float*)d_in[3];
  const float* w_l0 = (const float*)d_in[4];
  const float* w_r0 = (const float*)d_in[5];
  const float* b0   = (const float*)d_in[6];
  const float* w_l1 = (const float*)d_in[7];
  const float* w_r1 = (const float*)d_in[8];
  const float* b1   = (const float*)d_in[9];
  const float* w_l2 = (const float*)d_in[10];
  const float* w_r2 = (const float*)d_in[11];
  const float* b2   = (const float*)d_in[12];
  float* out = (float*)d_out;

  char* ws = (char*)d_ws;
  size_t off = 0;
  auto take = [&](size_t bytes) -> char* {
    char* p = ws + off;
    off = (off + bytes + 1023) & ~(size_t)1023;
    return p;
  };
  uint16_t* hb   = (uint16_t*)take((size_t)NN * 128 * 2);   // relu(lin_in), gemm1 input
  uint16_t* resb = (uint16_t*)take((size_t)NN * 128 * 2);   // 0.2*inp
  uint16_t* y0   = (uint16_t*)take((size_t)NN * 128 * 2);   // conv0 y (also xb staging, also y2)
  uint16_t* z0   = (uint16_t*)take((size_t)NN * 128 * 2);   // conv0 z (also z2 fp32 N*64)
  uint16_t* y1   = (uint16_t*)take((size_t)NN * 128 * 2);   // conv1 y
  uint16_t* z1   = (uint16_t*)take((size_t)NN * 128 * 2);   // conv1 z
  uint32_t* pairs = (uint32_t*)take((size_t)NE * 4);
  uint16_t* colx  = (uint16_t*)take((size_t)NE * 2);
  int* histG    = (int*)take((size_t)NBIN * ABLK * 4);
  int* binStart = (int*)take((size_t)(NBIN + 1) * 4);
  int* rowp     = (int*)take((size_t)(NN + 1) * 4);
  uint16_t* BpIn = (uint16_t*)take(128 * 128 * 2);
  uint16_t* Bp0  = (uint16_t*)take(128 * 256 * 2);
  uint16_t* Bp1  = (uint16_t*)take(128 * 256 * 2);
  uint16_t* Bp2  = (uint16_t*)take(128 * 128 * 2);
  uint16_t* y2 = y0;
  float*    z2 = (float*)z0;
  (void)ws_size; (void)in_sizes; (void)n_in; (void)out_size;

  // fused: cvt (x -> bf16 into y0) + bucket histogram + all weight packs
  k_prep<<<B_CVT + B_HIST + B_PIN + B_P0 + B_P1 + B_P2, 256, 0, stream>>>(
      x, (uint2*)y0, ei, histG, w_in, w_l0, w_r0, w_l1, w_r1, w_l2, w_r2, BpIn, Bp0, Bp1, Bp2);

  // CSR build: scan -> LDS bin-sort -> per-bucket counting sort (+ per-node src sort)
  k_scanG<<<1, 256, 0, stream>>>(histG, binStart);
  k_bin<<<ABLK, 256, 0, stream>>>(ei, histG, pairs);
  k_csr<<<NBIN, 256, 0, stream>>>(pairs, binStart, rowp, colx);

  // lin_in: xb(y0) -> hb, resb
  k_gemm<2, 0><<<1024, 256, 0, stream>>>(y0, BpIn, b_in, hb, resb);

  // conv0 gemm: hb -> y0, z0
  k_gemm<4, 1><<<1024, 256, 0, stream>>>(hb, Bp0, b0, y0, z0);

  // conv0 agg + conv1 gemm (fused): y0,z0,res -> y1,z1
  k_fused<4, 1><<<NN / 16, 256, 0, stream>>>((const uint32_t*)y0, (const uint32_t*)z0, (const uint32_t*)resb,
                                             colx, rowp, Bp1, b1, y1, z1, nullptr);

  // conv1 agg + conv2 gemm (fused): y1,z1,res -> y2(bf16), z2(fp32)
  k_fused<2, 2><<<NN / 16, 256, 0, stream>>>((const uint32_t*)y1, (const uint32_t*)z1, (const uint32_t*)resb,
                                             colx, rowp, Bp2, b2, y2, nullptr, z2);

  // conv2 agg + log_softmax
  agg_out<<<NN / 4, 256, 0, stream>>>(y2, z2, colx, rowp, out);
}

// Round 7
// 364.595 us; speedup vs baseline: 1.1080x; 1.1080x over previous
//
#include <hip/hip_runtime.h>
#include <stdint.h>

#define NN 50000
#define NE 800000
#define NBIN 196   // dst buckets of 256 nodes (dst >> 8)
#define ABLK 196   // blocks in hist/bin passes
#define EPB 4082   // edges per block: 196*4082 >= NE
#define BCAP 6144  // per-bucket LDS capacity (avg 4096)

typedef __attribute__((ext_vector_type(8))) short short8;
typedef __attribute__((ext_vector_type(4))) float floatx4;

__device__ __forceinline__ uint16_t f2bf(float f){
  union { float f; uint32_t u; } c; c.f = f;
  uint32_t u = c.u + 0x7FFFu + ((c.u >> 16) & 1u);
  return (uint16_t)(u >> 16);
}
__device__ __forceinline__ float bflo(uint32_t v){
  union { uint32_t u; float f; } c; c.u = v << 16; return c.f;
}
__device__ __forceinline__ float bfhi(uint32_t v){
  union { uint32_t u; float f; } c; c.u = v & 0xFFFF0000u; return c.f;
}
__device__ __forceinline__ float bfs(uint16_t v){
  union { uint32_t u; float f; } c; c.u = ((uint32_t)v) << 16; return c.f;
}

// ---------------- fused preprocessing: cvt + hist + weight packs ----------------
#define B_CVT 6250   // NN*128/4 / 256
#define B_HIST ABLK
#define B_PIN 64
#define B_P0  128
#define B_P1  128
#define B_P2  64

__device__ __forceinline__ void pack_one(int idx, const float* __restrict__ wl,
                                         const float* __restrict__ wr,
                                         uint16_t* __restrict__ bp,
                                         int ncolL, int ncolR, int NT){
  int j = idx & 7, lane = (idx >> 3) & 63, rest = idx >> 9;
  int nt = rest % NT, kt = rest / NT;
  int k = kt * 32 + ((lane >> 4) << 3) + j;
  int n = nt * 16 + (lane & 15);
  float v = (n < ncolL) ? wl[k * ncolL + n] : wr[k * ncolR + (n - ncolL)];
  bp[idx] = f2bf(v);
}

__global__ __launch_bounds__(256) void k_prep(const float* __restrict__ x, uint2* __restrict__ xb,
                                              const int* __restrict__ ei, int* __restrict__ histG,
                                              const float* __restrict__ w_in,
                                              const float* __restrict__ w_l0, const float* __restrict__ w_r0,
                                              const float* __restrict__ w_l1, const float* __restrict__ w_r1,
                                              const float* __restrict__ w_l2, const float* __restrict__ w_r2,
                                              uint16_t* __restrict__ bpIn, uint16_t* __restrict__ bp0,
                                              uint16_t* __restrict__ bp1, uint16_t* __restrict__ bp2){
  __shared__ int hsh[NBIN];
  int b = blockIdx.x;
  if (b < B_CVT){
    int i = b * 256 + threadIdx.x;
    if (i < NN * 128 / 4){
      float4 v = ((const float4*)x)[i];
      uint32_t lo = (uint32_t)f2bf(v.x) | ((uint32_t)f2bf(v.y) << 16);
      uint32_t hi = (uint32_t)f2bf(v.z) | ((uint32_t)f2bf(v.w) << 16);
      xb[i] = make_uint2(lo, hi);
    }
    return;
  }
  b -= B_CVT;
  if (b < B_HIST){
    for (int i = threadIdx.x; i < NBIN; i += 256) hsh[i] = 0;
    __syncthreads();
    int base = b * EPB;
    for (int k = threadIdx.x; k < EPB; k += 256){
      int e = base + k;
      if (e < NE) atomicAdd(&hsh[ei[NE + e] >> 8], 1);
    }
    __syncthreads();
    for (int i = threadIdx.x; i < NBIN; i += 256) histG[b * NBIN + i] = hsh[i];
    return;
  }
  b -= B_HIST;
  if (b < B_PIN){ pack_one(b * 256 + threadIdx.x, w_in, w_in, bpIn, 128, 0, 8); return; }
  b -= B_PIN;
  if (b < B_P0){ pack_one(b * 256 + threadIdx.x, w_l0, w_r0, bp0, 128, 128, 16); return; }
  b -= B_P0;
  if (b < B_P1){ pack_one(b * 256 + threadIdx.x, w_l1, w_r1, bp1, 128, 128, 16); return; }
  b -= B_P1;
  pack_one(b * 256 + threadIdx.x, w_l2, w_r2, bp2, 64, 64, 8);
}

// ---------------- pass A2: scan (coalesced [blk][bin] layout) ----------------
__global__ __launch_bounds__(256) void k_scanG(int* __restrict__ histG, int* __restrict__ binStart){
  __shared__ int s[256];
  int t = threadIdx.x;
  int tot = 0;
  if (t < NBIN){
    for (int b = 0; b < ABLK; ++b){
      int v = histG[b * NBIN + t];
      histG[b * NBIN + t] = tot;
      tot += v;
    }
  }
  s[t] = (t < NBIN) ? tot : 0;
  __syncthreads();
  #pragma unroll
  for (int off = 1; off < 256; off <<= 1){
    int u = (t >= off) ? s[t - off] : 0;
    __syncthreads();
    s[t] += u;
    __syncthreads();
  }
  int excl = s[t] - ((t < NBIN) ? tot : 0);
  if (t < NBIN){
    binStart[t] = excl;
    for (int b = 0; b < ABLK; ++b) histG[b * NBIN + t] += excl;
  }
  if (t == 0) binStart[NBIN] = NE;
}

// ---------------- pass A3: LDS bin-sort, contiguous-run writes ----------------
__global__ __launch_bounds__(256) void k_bin(const int* __restrict__ ei, const int* __restrict__ histG,
                                             uint32_t* __restrict__ pairs){
  __shared__ int h[NBIN], loc[NBIN], cur[NBIN], gof[NBIN];
  __shared__ int sc[256];
  __shared__ uint32_t st[EPB];
  int t = threadIdx.x;
  int base = blockIdx.x * EPB;
  for (int i = t; i < NBIN; i += 256) h[i] = 0;
  __syncthreads();
  for (int k = t; k < EPB; k += 256){
    int e = base + k;
    if (e < NE) atomicAdd(&h[ei[NE + e] >> 8], 1);
  }
  __syncthreads();
  int cv = (t < NBIN) ? h[t] : 0;
  sc[t] = cv;
  __syncthreads();
  #pragma unroll
  for (int off = 1; off < 256; off <<= 1){
    int u = (t >= off) ? sc[t - off] : 0;
    __syncthreads();
    sc[t] += u;
    __syncthreads();
  }
  if (t < NBIN){
    int excl = sc[t] - cv;
    loc[t] = excl;
    cur[t] = excl;
    gof[t] = histG[blockIdx.x * NBIN + t];
  }
  __syncthreads();
  for (int k = t; k < EPB; k += 256){
    int e = base + k;
    if (e < NE){
      int d = ei[NE + e];
      int s0 = ei[e];
      int pos = atomicAdd(&cur[d >> 8], 1);
      st[pos] = (uint32_t)s0 | ((uint32_t)d << 16);
    }
  }
  __syncthreads();
  int cnt = min(EPB, NE - base);
  for (int k = t; k < cnt; k += 256){
    uint32_t v = st[k];
    int bin = (int)(v >> 24);
    pairs[gof[bin] + (k - loc[bin])] = v;
  }
}

// ---------------- pass B: per-bucket counting sort -> rowp + colx(u16, src-sorted) ----------------
__global__ __launch_bounds__(256) void k_csr(const uint32_t* __restrict__ pairs, const int* __restrict__ binStart,
                                             int* __restrict__ rowp, uint16_t* __restrict__ colx){
  __shared__ uint32_t pl[BCAP];
  __shared__ uint16_t stg[BCAP];
  __shared__ int h[256], sc[256];
  int i = blockIdx.x, t = threadIdx.x;
  int p0 = binStart[i], p1 = binStart[i + 1];
  int cnt = min(p1 - p0, BCAP);
  for (int k = t; k < cnt; k += 256) pl[k] = pairs[p0 + k];
  h[t] = 0;
  __syncthreads();
  for (int k = t; k < cnt; k += 256) atomicAdd(&h[(pl[k] >> 16) & 255], 1);
  __syncthreads();
  int cv = h[t];
  sc[t] = cv;
  __syncthreads();
  #pragma unroll
  for (int off = 1; off < 256; off <<= 1){
    int u = (t >= off) ? sc[t - off] : 0;
    __syncthreads();
    sc[t] += u;
    __syncthreads();
  }
  int excl = sc[t] - cv;
  int n0 = i << 8;
  int nc = min(256, NN - n0);
  if (t < nc) rowp[n0 + t] = p0 + excl;
  if (i == NBIN - 1 && t == 0) rowp[NN] = NE;
  h[t] = excl;   // becomes cursor
  __syncthreads();
  for (int k = t; k < cnt; k += 256){
    uint32_t v = pl[k];
    int pos = atomicAdd(&h[(v >> 16) & 255], 1);
    stg[pos] = (uint16_t)(v & 0xFFFFu);
  }
  __syncthreads();
  // per-node insertion sort by src (gather locality; sum order irrelevant)
  {
    int st0 = excl, cnt0 = cv;
    for (int a = st0 + 1; a < st0 + cnt0; ++a){
      uint16_t key = stg[a];
      int b2 = a - 1;
      while (b2 >= st0 && stg[b2] > key){ stg[b2 + 1] = stg[b2]; --b2; }
      stg[b2 + 1] = key;
    }
  }
  __syncthreads();
  for (int k = t; k < cnt; k += 256) colx[p0 + k] = stg[k];
}

// ------------- fused lin_in + conv0 GEMM (dense, balanced -> safe to fuse) -------------
// xb -> h = relu(x@Win+b) (kept in LDS), resb = bf16(0.2*(x@Win+b)); then y0/z0 = h@[Wl0|Wr0]
__global__ __launch_bounds__(256) void k_lin0(const uint16_t* __restrict__ xb,
                                              const uint16_t* __restrict__ BpIn, const float* __restrict__ b_in,
                                              const uint16_t* __restrict__ Bp0, const float* __restrict__ b0,
                                              uint16_t* __restrict__ resb, uint16_t* __restrict__ y0,
                                              uint16_t* __restrict__ z0){
  __shared__ uint16_t ash[16 * 136];   // 16 rows x 128 cols, stride 136 (16B-aligned rows)
  int lane = threadIdx.x & 63, wave = threadIdx.x >> 6;
  short8 bIn[4][2], bC0[4][4];
  #pragma unroll
  for (int kt = 0; kt < 4; ++kt){
    #pragma unroll
    for (int n = 0; n < 2; ++n)
      bIn[kt][n] = *(const short8*)(BpIn + (size_t)((kt * 8 + wave * 2 + n) * 64 + lane) * 8);
    #pragma unroll
    for (int n = 0; n < 4; ++n)
      bC0[kt][n] = *(const short8*)(Bp0 + (size_t)((kt * 16 + wave * 4 + n) * 64 + lane) * 8);
  }
  int m = lane & 15, quad = lane >> 4;
  int r0 = blockIdx.x * 16;
  const uint16_t* arow = xb + (size_t)(r0 + m) * 128 + quad * 8;
  short8 af[4];
  #pragma unroll
  for (int kt = 0; kt < 4; ++kt) af[kt] = *(const short8*)(arow + kt * 32);
  floatx4 accH[2];
  #pragma unroll
  for (int n = 0; n < 2; ++n) accH[n] = (floatx4){0.f, 0.f, 0.f, 0.f};
  #pragma unroll
  for (int kt = 0; kt < 4; ++kt)
    #pragma unroll
    for (int n = 0; n < 2; ++n)
      accH[n] = __builtin_amdgcn_mfma_f32_16x16x32_bf16(af[kt], bIn[kt][n], accH[n], 0, 0, 0);
  int rbase = r0 + quad * 4;
  #pragma unroll
  for (int n = 0; n < 2; ++n){
    int c = (wave * 2 + n) * 16 + m;
    float bi = b_in[c];
    #pragma unroll
    for (int i = 0; i < 4; ++i){
      float hh = accH[n][i] + bi;
      int row = rbase + i;
      resb[(size_t)row * 128 + c] = f2bf(0.2f * hh);
      ash[(quad * 4 + i) * 136 + c] = f2bf(fmaxf(hh, 0.f));
    }
  }
  __syncthreads();
  short8 af2[4];
  #pragma unroll
  for (int kt = 0; kt < 4; ++kt)
    af2[kt] = *(const short8*)&ash[m * 136 + quad * 8 + kt * 32];
  floatx4 acc[4];
  #pragma unroll
  for (int n = 0; n < 4; ++n) acc[n] = (floatx4){0.f, 0.f, 0.f, 0.f};
  #pragma unroll
  for (int kt = 0; kt < 4; ++kt)
    #pragma unroll
    for (int n = 0; n < 4; ++n)
      acc[n] = __builtin_amdgcn_mfma_f32_16x16x32_bf16(af2[kt], bC0[kt][n], acc[n], 0, 0, 0);
  #pragma unroll
  for (int n = 0; n < 4; ++n){
    int c = (wave * 4 + n) * 16 + m;
    #pragma unroll
    for (int i = 0; i < 4; ++i){
      float v = acc[n][i];
      int row = rbase + i;
      if (c < 128) y0[(size_t)row * 128 + c] = f2bf(v);
      else         z0[(size_t)row * 128 + (c - 128)] = f2bf(v + b0[c - 128]);
    }
  }
}

// ------------- GEMM: A[N,128]bf16 @ Bp[128, NCOL] -> epilogue -------------
// MODE 1: NCOL=256: c<128 -> o0=bf16 [y]; else o1=bf16(+bias) [z]
// MODE 2: NCOL=128: c<64  -> o0=bf16 [y2]; else o2=fp32(+bias) [z2]
template<int NTW, int MODE>
__global__ __launch_bounds__(256) void k_gemm(const uint16_t* __restrict__ A, const uint16_t* __restrict__ Bp,
                                              const float* __restrict__ bias,
                                              uint16_t* __restrict__ o0, uint16_t* __restrict__ o1,
                                              float* __restrict__ o2){
  const int NTT = 4 * NTW;
  int lane = threadIdx.x & 63;
  int wave = threadIdx.x >> 6;
  short8 bfrag[4][NTW];
  #pragma unroll
  for (int kt = 0; kt < 4; ++kt)
    #pragma unroll
    for (int n = 0; n < NTW; ++n)
      bfrag[kt][n] = *(const short8*)(Bp + (size_t)((kt * NTT + wave * NTW + n) * 64 + lane) * 8);

  int m = lane & 15, quad = lane >> 4;
  const int nrt = NN / 16;
  for (int rt = blockIdx.x; rt < nrt; rt += gridDim.x){
    int r0 = rt * 16;
    const uint16_t* arow = A + (size_t)(r0 + m) * 128 + quad * 8;
    short8 af[4];
    #pragma unroll
    for (int kt = 0; kt < 4; ++kt) af[kt] = *(const short8*)(arow + kt * 32);
    floatx4 acc[NTW];
    #pragma unroll
    for (int n = 0; n < NTW; ++n) acc[n] = (floatx4){0.f, 0.f, 0.f, 0.f};
    #pragma unroll
    for (int kt = 0; kt < 4; ++kt)
      #pragma unroll
      for (int n = 0; n < NTW; ++n)
        acc[n] = __builtin_amdgcn_mfma_f32_16x16x32_bf16(af[kt], bfrag[kt][n], acc[n], 0, 0, 0);

    int rbase = r0 + quad * 4;
    #pragma unroll
    for (int n = 0; n < NTW; ++n){
      int c = (wave * NTW + n) * 16 + m;
      #pragma unroll
      for (int i = 0; i < 4; ++i){
        float v = acc[n][i];
        int row = rbase + i;
        if (MODE == 1){
          if (c < 128) o0[(size_t)row * 128 + c] = f2bf(v);
          else         o1[(size_t)row * 128 + (c - 128)] = f2bf(v + bias[c - 128]);
        } else {
          if (c < 64) o0[(size_t)row * 64 + c] = f2bf(v);
          else        o2[(size_t)row * 64 + (c - 64)] = v + bias[c - 64];
        }
      }
    }
  }
}

// ------------- aggregation (pull, CSR): one wave per node, 8-deep unroll -------------
__global__ __launch_bounds__(256) void agg_mid(const uint32_t* __restrict__ yb, const uint32_t* __restrict__ zb,
                                               const uint32_t* __restrict__ resb,
                                               const uint16_t* __restrict__ colx, const int* __restrict__ rowp,
                                               uint32_t* __restrict__ hb_out){
  int wid = blockIdx.x * 4 + (threadIdx.x >> 6);
  if (wid >= NN) return;
  int lane = threadIdx.x & 63;
  int e0 = rowp[wid], e1 = rowp[wid + 1];
  float a0 = 0.f, a1 = 0.f;
  int e = e0;
  for (; e + 8 <= e1; e += 8){
    uint32_t v0 = yb[(size_t)colx[e]     * 64 + lane];
    uint32_t v1 = yb[(size_t)colx[e + 1] * 64 + lane];
    uint32_t v2 = yb[(size_t)colx[e + 2] * 64 + lane];
    uint32_t v3 = yb[(size_t)colx[e + 3] * 64 + lane];
    uint32_t v4 = yb[(size_t)colx[e + 4] * 64 + lane];
    uint32_t v5 = yb[(size_t)colx[e + 5] * 64 + lane];
    uint32_t v6 = yb[(size_t)colx[e + 6] * 64 + lane];
    uint32_t v7 = yb[(size_t)colx[e + 7] * 64 + lane];
    a0 += bflo(v0) + bflo(v1) + bflo(v2) + bflo(v3) + bflo(v4) + bflo(v5) + bflo(v6) + bflo(v7);
    a1 += bfhi(v0) + bfhi(v1) + bfhi(v2) + bfhi(v3) + bfhi(v4) + bfhi(v5) + bfhi(v6) + bfhi(v7);
  }
  for (; e < e1; ++e){
    uint32_t v = yb[(size_t)colx[e] * 64 + lane];
    a0 += bflo(v); a1 += bfhi(v);
  }
  int deg = e1 - e0;
  float inv = deg > 0 ? 1.f / (float)deg : 0.f;
  uint32_t zv = zb[(size_t)wid * 64 + lane];
  uint32_t rv = resb[(size_t)wid * 64 + lane];
  float v0 = fmaxf(a0 * inv + bflo(zv), 0.f) + bflo(rv);
  float v1 = fmaxf(a1 * inv + bfhi(zv), 0.f) + bfhi(rv);
  hb_out[(size_t)wid * 64 + lane] = (uint32_t)f2bf(v0) | ((uint32_t)f2bf(v1) << 16);
}

__global__ __launch_bounds__(256) void agg_out(const uint16_t* __restrict__ yb2, const float* __restrict__ z2,
                                               const uint16_t* __restrict__ colx, const int* __restrict__ rowp,
                                               float* __restrict__ out){
  int wid = blockIdx.x * 4 + (threadIdx.x >> 6);
  if (wid >= NN) return;
  int lane = threadIdx.x & 63;
  int e0 = rowp[wid], e1 = rowp[wid + 1];
  float a = 0.f;
  int e = e0;
  for (; e + 8 <= e1; e += 8){
    a += bfs(yb2[(size_t)colx[e]     * 64 + lane]) + bfs(yb2[(size_t)colx[e + 1] * 64 + lane])
       + bfs(yb2[(size_t)colx[e + 2] * 64 + lane]) + bfs(yb2[(size_t)colx[e + 3] * 64 + lane])
       + bfs(yb2[(size_t)colx[e + 4] * 64 + lane]) + bfs(yb2[(size_t)colx[e + 5] * 64 + lane])
       + bfs(yb2[(size_t)colx[e + 6] * 64 + lane]) + bfs(yb2[(size_t)colx[e + 7] * 64 + lane]);
  }
  for (; e < e1; ++e) a += bfs(yb2[(size_t)colx[e] * 64 + lane]);
  int deg = e1 - e0;
  float inv = deg > 0 ? 1.f / (float)deg : 0.f;
  float v = a * inv + z2[(size_t)wid * 64 + lane];
  float mx = v;
  #pragma unroll
  for (int off = 32; off; off >>= 1) mx = fmaxf(mx, __shfl_xor(mx, off, 64));
  float ex = __expf(v - mx);
  float sm = ex;
  #pragma unroll
  for (int off = 32; off; off >>= 1) sm += __shfl_xor(sm, off, 64);
  out[(size_t)wid * 64 + lane] = (v - mx) - __logf(sm);
}

extern "C" void kernel_launch(void* const* d_in, const int* in_sizes, int n_in,
                              void* d_out, int out_size, void* d_ws, size_t ws_size,
                              hipStream_t stream){
  const float* x    = (const float*)d_in[0];
  const int*   ei   = (const int*)d_in[1];
  const float* w_in = (const float*)d_in[2];
  const float* b_in = (const float*)d_in[3];
  const float* w_l0 = (const float*)d_in[4];
  const float* w_r0 = (const float*)d_in[5];
  const float* b0   = (const float*)d_in[6];
  const float* w_l1 = (const float*)d_in[7];
  const float* w_r1 = (const float*)d_in[8];
  const float* b1   = (const float*)d_in[9];
  const float* w_l2 = (const float*)d_in[10];
  const float* w_r2 = (const float*)d_in[11];
  const float* b2   = (const float*)d_in[12];
  float* out = (float*)d_out;

  char* ws = (char*)d_ws;
  size_t off = 0;
  auto take = [&](size_t bytes) -> char* {
    char* p = ws + off;
    off = (off + bytes + 1023) & ~(size_t)1023;
    return p;
  };
  uint16_t* xb   = (uint16_t*)take((size_t)NN * 128 * 2);   // bf16(x)
  uint16_t* hb   = (uint16_t*)take((size_t)NN * 128 * 2);   // agg outputs
  uint16_t* resb = (uint16_t*)take((size_t)NN * 128 * 2);   // 0.2*inp
  uint16_t* y0   = (uint16_t*)take((size_t)NN * 128 * 2);   // y (reused each conv)
  uint16_t* z0   = (uint16_t*)take((size_t)NN * 128 * 2);   // z (reused; fp32 z2 at end)
  uint32_t* pairs = (uint32_t*)take((size_t)NE * 4);
  uint16_t* colx  = (uint16_t*)take((size_t)NE * 2);
  int* histG    = (int*)take((size_t)NBIN * ABLK * 4);
  int* binStart = (int*)take((size_t)(NBIN + 1) * 4);
  int* rowp     = (int*)take((size_t)(NN + 1) * 4);
  uint16_t* BpIn = (uint16_t*)take(128 * 128 * 2);
  uint16_t* Bp0  = (uint16_t*)take(128 * 256 * 2);
  uint16_t* Bp1  = (uint16_t*)take(128 * 256 * 2);
  uint16_t* Bp2  = (uint16_t*)take(128 * 128 * 2);
  uint16_t* y2 = y0;
  float*    z2 = (float*)z0;
  (void)ws_size; (void)in_sizes; (void)n_in; (void)out_size;

  // fused: cvt (x -> bf16 into xb) + bucket histogram + all weight packs
  k_prep<<<B_CVT + B_HIST + B_PIN + B_P0 + B_P1 + B_P2, 256, 0, stream>>>(
      x, (uint2*)xb, ei, histG, w_in, w_l0, w_r0, w_l1, w_r1, w_l2, w_r2, BpIn, Bp0, Bp1, Bp2);

  // CSR build
  k_scanG<<<1, 256, 0, stream>>>(histG, binStart);
  k_bin<<<ABLK, 256, 0, stream>>>(ei, histG, pairs);
  k_csr<<<NBIN, 256, 0, stream>>>(pairs, binStart, rowp, colx);

  // lin_in + conv0 gemm (fused dense): xb -> resb, y0, z0
  k_lin0<<<NN / 16, 256, 0, stream>>>(xb, BpIn, b_in, Bp0, b0, resb, y0, z0);

  // conv0 agg: y0,z0,res -> hb
  agg_mid<<<NN / 4, 256, 0, stream>>>((const uint32_t*)y0, (const uint32_t*)z0, (const uint32_t*)resb,
                                      colx, rowp, (uint32_t*)hb);
  // conv1 gemm: hb -> y0, z0
  k_gemm<4, 1><<<1024, 256, 0, stream>>>(hb, Bp1, b1, y0, z0, nullptr);

  // conv1 agg: y0,z0,res -> hb
  agg_mid<<<NN / 4, 256, 0, stream>>>((const uint32_t*)y0, (const uint32_t*)z0, (const uint32_t*)resb,
                                      colx, rowp, (uint32_t*)hb);
  // conv2 gemm: hb -> y2(bf16 64c), z2(fp32 64c)
  k_gemm<2, 2><<<1024, 256, 0, stream>>>(hb, Bp2, b2, y2, nullptr, z2);

  // conv2 agg + log_softmax
  agg_out<<<NN / 4, 256, 0, stream>>>(y2, z2, colx, rowp, out);
}

// Round 8
// 307.615 us; speedup vs baseline: 1.3133x; 1.1852x over previous
//
#include <hip/hip_runtime.h>
#include <stdint.h>

#define NN 50000
#define NE 800000
#define NBIN 196   // dst buckets of 256 nodes (dst >> 8)
#define ABLK 196   // blocks in hist/bin passes
#define EPB 4082   // edges per block: 196*4082 >= NE
#define BCAP 6144  // per-bucket LDS capacity (avg 4096)

typedef __attribute__((ext_vector_type(8))) short short8;
typedef __attribute__((ext_vector_type(4))) float floatx4;

__device__ __forceinline__ uint16_t f2bf(float f){
  union { float f; uint32_t u; } c; c.f = f;
  uint32_t u = c.u + 0x7FFFu + ((c.u >> 16) & 1u);
  return (uint16_t)(u >> 16);
}
__device__ __forceinline__ float bflo(uint32_t v){
  union { uint32_t u; float f; } c; c.u = v << 16; return c.f;
}
__device__ __forceinline__ float bfhi(uint32_t v){
  union { uint32_t u; float f; } c; c.u = v & 0xFFFF0000u; return c.f;
}

// ---------------- fused preprocessing: cvt + hist + weight packs ----------------
#define B_CVT 6250   // NN*128/4 / 256
#define B_HIST ABLK
#define B_PIN 64
#define B_P0  128
#define B_P1  128
#define B_P2  64

__device__ __forceinline__ void pack_one(int idx, const float* __restrict__ wl,
                                         const float* __restrict__ wr,
                                         uint16_t* __restrict__ bp,
                                         int ncolL, int ncolR, int NT){
  int j = idx & 7, lane = (idx >> 3) & 63, rest = idx >> 9;
  int nt = rest % NT, kt = rest / NT;
  int k = kt * 32 + ((lane >> 4) << 3) + j;
  int n = nt * 16 + (lane & 15);
  float v = (n < ncolL) ? wl[k * ncolL + n] : wr[k * ncolR + (n - ncolL)];
  bp[idx] = f2bf(v);
}

__global__ __launch_bounds__(256) void k_prep(const float* __restrict__ x, uint2* __restrict__ xb,
                                              const int* __restrict__ ei, int* __restrict__ histG,
                                              const float* __restrict__ w_in,
                                              const float* __restrict__ w_l0, const float* __restrict__ w_r0,
                                              const float* __restrict__ w_l1, const float* __restrict__ w_r1,
                                              const float* __restrict__ w_l2, const float* __restrict__ w_r2,
                                              uint16_t* __restrict__ bpIn, uint16_t* __restrict__ bp0,
                                              uint16_t* __restrict__ bp1, uint16_t* __restrict__ bp2){
  __shared__ int hsh[NBIN];
  int b = blockIdx.x;
  if (b < B_CVT){
    int i = b * 256 + threadIdx.x;
    if (i < NN * 128 / 4){
      float4 v = ((const float4*)x)[i];
      uint32_t lo = (uint32_t)f2bf(v.x) | ((uint32_t)f2bf(v.y) << 16);
      uint32_t hi = (uint32_t)f2bf(v.z) | ((uint32_t)f2bf(v.w) << 16);
      xb[i] = make_uint2(lo, hi);
    }
    return;
  }
  b -= B_CVT;
  if (b < B_HIST){
    for (int i = threadIdx.x; i < NBIN; i += 256) hsh[i] = 0;
    __syncthreads();
    int base = b * EPB;
    for (int k = threadIdx.x; k < EPB; k += 256){
      int e = base + k;
      if (e < NE) atomicAdd(&hsh[ei[NE + e] >> 8], 1);
    }
    __syncthreads();
    for (int i = threadIdx.x; i < NBIN; i += 256) histG[b * NBIN + i] = hsh[i];
    return;
  }
  b -= B_HIST;
  if (b < B_PIN){ pack_one(b * 256 + threadIdx.x, w_in, w_in, bpIn, 128, 0, 8); return; }
  b -= B_PIN;
  if (b < B_P0){ pack_one(b * 256 + threadIdx.x, w_l0, w_r0, bp0, 128, 128, 16); return; }
  b -= B_P0;
  if (b < B_P1){ pack_one(b * 256 + threadIdx.x, w_l1, w_r1, bp1, 128, 128, 16); return; }
  b -= B_P1;
  pack_one(b * 256 + threadIdx.x, w_l2, w_r2, bp2, 64, 64, 8);
}

// ---------------- pass A2: scan (coalesced [blk][bin] layout) ----------------
__global__ __launch_bounds__(256) void k_scanG(int* __restrict__ histG, int* __restrict__ binStart){
  __shared__ int s[256];
  int t = threadIdx.x;
  int tot = 0;
  if (t < NBIN){
    for (int b = 0; b < ABLK; ++b){
      int v = histG[b * NBIN + t];
      histG[b * NBIN + t] = tot;
      tot += v;
    }
  }
  s[t] = (t < NBIN) ? tot : 0;
  __syncthreads();
  #pragma unroll
  for (int off = 1; off < 256; off <<= 1){
    int u = (t >= off) ? s[t - off] : 0;
    __syncthreads();
    s[t] += u;
    __syncthreads();
  }
  int excl = s[t] - ((t < NBIN) ? tot : 0);
  if (t < NBIN){
    binStart[t] = excl;
    for (int b = 0; b < ABLK; ++b) histG[b * NBIN + t] += excl;
  }
  if (t == 0) binStart[NBIN] = NE;
}

// ---------------- pass A3: LDS bin-sort, contiguous-run writes ----------------
__global__ __launch_bounds__(256) void k_bin(const int* __restrict__ ei, const int* __restrict__ histG,
                                             uint32_t* __restrict__ pairs){
  __shared__ int h[NBIN], loc[NBIN], cur[NBIN], gof[NBIN];
  __shared__ int sc[256];
  __shared__ uint32_t st[EPB];
  int t = threadIdx.x;
  int base = blockIdx.x * EPB;
  for (int i = t; i < NBIN; i += 256) h[i] = 0;
  __syncthreads();
  for (int k = t; k < EPB; k += 256){
    int e = base + k;
    if (e < NE) atomicAdd(&h[ei[NE + e] >> 8], 1);
  }
  __syncthreads();
  int cv = (t < NBIN) ? h[t] : 0;
  sc[t] = cv;
  __syncthreads();
  #pragma unroll
  for (int off = 1; off < 256; off <<= 1){
    int u = (t >= off) ? sc[t - off] : 0;
    __syncthreads();
    sc[t] += u;
    __syncthreads();
  }
  if (t < NBIN){
    int excl = sc[t] - cv;
    loc[t] = excl;
    cur[t] = excl;
    gof[t] = histG[blockIdx.x * NBIN + t];
  }
  __syncthreads();
  for (int k = t; k < EPB; k += 256){
    int e = base + k;
    if (e < NE){
      int d = ei[NE + e];
      int s0 = ei[e];
      int pos = atomicAdd(&cur[d >> 8], 1);
      st[pos] = (uint32_t)s0 | ((uint32_t)d << 16);
    }
  }
  __syncthreads();
  int cnt = min(EPB, NE - base);
  for (int k = t; k < cnt; k += 256){
    uint32_t v = st[k];
    int bin = (int)(v >> 24);
    pairs[gof[bin] + (k - loc[bin])] = v;
  }
}

// ---------------- pass B: per-bucket counting sort -> rowp + colx(u16) ----------------
__global__ __launch_bounds__(256) void k_csr(const uint32_t* __restrict__ pairs, const int* __restrict__ binStart,
                                             int* __restrict__ rowp, uint16_t* __restrict__ colx){
  __shared__ uint32_t pl[BCAP];
  __shared__ uint16_t stg[BCAP];
  __shared__ int h[256], sc[256];
  int i = blockIdx.x, t = threadIdx.x;
  int p0 = binStart[i], p1 = binStart[i + 1];
  int cnt = min(p1 - p0, BCAP);
  for (int k = t; k < cnt; k += 256) pl[k] = pairs[p0 + k];
  h[t] = 0;
  __syncthreads();
  for (int k = t; k < cnt; k += 256) atomicAdd(&h[(pl[k] >> 16) & 255], 1);
  __syncthreads();
  int cv = h[t];
  sc[t] = cv;
  __syncthreads();
  #pragma unroll
  for (int off = 1; off < 256; off <<= 1){
    int u = (t >= off) ? sc[t - off] : 0;
    __syncthreads();
    sc[t] += u;
    __syncthreads();
  }
  int excl = sc[t] - cv;
  int n0 = i << 8;
  int nc = min(256, NN - n0);
  if (t < nc) rowp[n0 + t] = p0 + excl;
  if (i == NBIN - 1 && t == 0) rowp[NN] = NE;
  h[t] = excl;   // becomes cursor
  __syncthreads();
  for (int k = t; k < cnt; k += 256){
    uint32_t v = pl[k];
    int pos = atomicAdd(&h[(v >> 16) & 255], 1);
    stg[pos] = (uint16_t)(v & 0xFFFFu);
  }
  __syncthreads();
  for (int k = t; k < cnt; k += 256) colx[p0 + k] = stg[k];
}

// ------------- fused lin_in + conv0 GEMM -------------
__global__ __launch_bounds__(256) void k_lin0(const uint16_t* __restrict__ xb,
                                              const uint16_t* __restrict__ BpIn, const float* __restrict__ b_in,
                                              const uint16_t* __restrict__ Bp0, const float* __restrict__ b0,
                                              uint16_t* __restrict__ resb, uint16_t* __restrict__ y0,
                                              uint16_t* __restrict__ z0){
  __shared__ uint16_t ash[16 * 136];
  int lane = threadIdx.x & 63, wave = threadIdx.x >> 6;
  short8 bIn[4][2], bC0[4][4];
  #pragma unroll
  for (int kt = 0; kt < 4; ++kt){
    #pragma unroll
    for (int n = 0; n < 2; ++n)
      bIn[kt][n] = *(const short8*)(BpIn + (size_t)((kt * 8 + wave * 2 + n) * 64 + lane) * 8);
    #pragma unroll
    for (int n = 0; n < 4; ++n)
      bC0[kt][n] = *(const short8*)(Bp0 + (size_t)((kt * 16 + wave * 4 + n) * 64 + lane) * 8);
  }
  int m = lane & 15, quad = lane >> 4;
  int r0 = blockIdx.x * 16;
  const uint16_t* arow = xb + (size_t)(r0 + m) * 128 + quad * 8;
  short8 af[4];
  #pragma unroll
  for (int kt = 0; kt < 4; ++kt) af[kt] = *(const short8*)(arow + kt * 32);
  floatx4 accH[2];
  #pragma unroll
  for (int n = 0; n < 2; ++n) accH[n] = (floatx4){0.f, 0.f, 0.f, 0.f};
  #pragma unroll
  for (int kt = 0; kt < 4; ++kt)
    #pragma unroll
    for (int n = 0; n < 2; ++n)
      accH[n] = __builtin_amdgcn_mfma_f32_16x16x32_bf16(af[kt], bIn[kt][n], accH[n], 0, 0, 0);
  int rbase = r0 + quad * 4;
  #pragma unroll
  for (int n = 0; n < 2; ++n){
    int c = (wave * 2 + n) * 16 + m;
    float bi = b_in[c];
    #pragma unroll
    for (int i = 0; i < 4; ++i){
      float hh = accH[n][i] + bi;
      int row = rbase + i;
      resb[(size_t)row * 128 + c] = f2bf(0.2f * hh);
      ash[(quad * 4 + i) * 136 + c] = f2bf(fmaxf(hh, 0.f));
    }
  }
  __syncthreads();
  short8 af2[4];
  #pragma unroll
  for (int kt = 0; kt < 4; ++kt)
    af2[kt] = *(const short8*)&ash[m * 136 + quad * 8 + kt * 32];
  floatx4 acc[4];
  #pragma unroll
  for (int n = 0; n < 4; ++n) acc[n] = (floatx4){0.f, 0.f, 0.f, 0.f};
  #pragma unroll
  for (int kt = 0; kt < 4; ++kt)
    #pragma unroll
    for (int n = 0; n < 4; ++n)
      acc[n] = __builtin_amdgcn_mfma_f32_16x16x32_bf16(af2[kt], bC0[kt][n], acc[n], 0, 0, 0);
  #pragma unroll
  for (int n = 0; n < 4; ++n){
    int c = (wave * 4 + n) * 16 + m;
    #pragma unroll
    for (int i = 0; i < 4; ++i){
      float v = acc[n][i];
      int row = rbase + i;
      if (c < 128) y0[(size_t)row * 128 + c] = f2bf(v);
      else         z0[(size_t)row * 128 + (c - 128)] = f2bf(v + b0[c - 128]);
    }
  }
}

// ------------- GEMM: A[N,128]bf16 @ Bp[128, NCOL] -> epilogue -------------
template<int NTW, int MODE>
__global__ __launch_bounds__(256) void k_gemm(const uint16_t* __restrict__ A, const uint16_t* __restrict__ Bp,
                                              const float* __restrict__ bias,
                                              uint16_t* __restrict__ o0, uint16_t* __restrict__ o1,
                                              float* __restrict__ o2){
  const int NTT = 4 * NTW;
  int lane = threadIdx.x & 63;
  int wave = threadIdx.x >> 6;
  short8 bfrag[4][NTW];
  #pragma unroll
  for (int kt = 0; kt < 4; ++kt)
    #pragma unroll
    for (int n = 0; n < NTW; ++n)
      bfrag[kt][n] = *(const short8*)(Bp + (size_t)((kt * NTT + wave * NTW + n) * 64 + lane) * 8);

  int m = lane & 15, quad = lane >> 4;
  const int nrt = NN / 16;
  for (int rt = blockIdx.x; rt < nrt; rt += gridDim.x){
    int r0 = rt * 16;
    const uint16_t* arow = A + (size_t)(r0 + m) * 128 + quad * 8;
    short8 af[4];
    #pragma unroll
    for (int kt = 0; kt < 4; ++kt) af[kt] = *(const short8*)(arow + kt * 32);
    floatx4 acc[NTW];
    #pragma unroll
    for (int n = 0; n < NTW; ++n) acc[n] = (floatx4){0.f, 0.f, 0.f, 0.f};
    #pragma unroll
    for (int kt = 0; kt < 4; ++kt)
      #pragma unroll
      for (int n = 0; n < NTW; ++n)
        acc[n] = __builtin_amdgcn_mfma_f32_16x16x32_bf16(af[kt], bfrag[kt][n], acc[n], 0, 0, 0);

    int rbase = r0 + quad * 4;
    #pragma unroll
    for (int n = 0; n < NTW; ++n){
      int c = (wave * NTW + n) * 16 + m;
      #pragma unroll
      for (int i = 0; i < 4; ++i){
        float v = acc[n][i];
        int row = rbase + i;
        if (MODE == 1){
          if (c < 128) o0[(size_t)row * 128 + c] = f2bf(v);
          else         o1[(size_t)row * 128 + (c - 128)] = f2bf(v + bias[c - 128]);
        } else {
          if (c < 64) o0[(size_t)row * 64 + c] = f2bf(v);
          else        o2[(size_t)row * 64 + (c - 64)] = v + bias[c - 64];
        }
      }
    }
  }
}

// ------------- aggregation: one wave per node; half-wave (32-lane) per edge, uint2 loads -------------
// lane = 32*half + sub; half h processes edges e0+h, e0+h+2, ...; sub handles dims 4*sub..4*sub+3
__global__ __launch_bounds__(256) void agg_mid(const uint2* __restrict__ yb, const uint2* __restrict__ zb,
                                               const uint2* __restrict__ resb,
                                               const uint16_t* __restrict__ colx, const int* __restrict__ rowp,
                                               uint2* __restrict__ hb_out){
  int wid = blockIdx.x * 4 + (threadIdx.x >> 6);
  if (wid >= NN) return;
  int lane = threadIdx.x & 63;
  int half = lane >> 5, sub = lane & 31;
  int e0 = rowp[wid], e1 = rowp[wid + 1];
  float a0 = 0.f, a1 = 0.f, a2 = 0.f, a3 = 0.f;
  int e = e0 + half;
  for (; e + 6 < e1; e += 8){
    uint2 v0 = yb[(size_t)colx[e]     * 32 + sub];
    uint2 v1 = yb[(size_t)colx[e + 2] * 32 + sub];
    uint2 v2 = yb[(size_t)colx[e + 4] * 32 + sub];
    uint2 v3 = yb[(size_t)colx[e + 6] * 32 + sub];
    a0 += bflo(v0.x) + bflo(v1.x) + bflo(v2.x) + bflo(v3.x);
    a1 += bfhi(v0.x) + bfhi(v1.x) + bfhi(v2.x) + bfhi(v3.x);
    a2 += bflo(v0.y) + bflo(v1.y) + bflo(v2.y) + bflo(v3.y);
    a3 += bfhi(v0.y) + bfhi(v1.y) + bfhi(v2.y) + bfhi(v3.y);
  }
  for (; e < e1; e += 2){
    uint2 v = yb[(size_t)colx[e] * 32 + sub];
    a0 += bflo(v.x); a1 += bfhi(v.x); a2 += bflo(v.y); a3 += bfhi(v.y);
  }
  // combine the two half-waves (same node, same dims)
  a0 += __shfl_xor(a0, 32, 64);
  a1 += __shfl_xor(a1, 32, 64);
  a2 += __shfl_xor(a2, 32, 64);
  a3 += __shfl_xor(a3, 32, 64);
  int deg = e1 - e0;
  float inv = deg > 0 ? 1.f / (float)deg : 0.f;
  if (half == 0){
    uint2 zv = zb[(size_t)wid * 32 + sub];
    uint2 rv = resb[(size_t)wid * 32 + sub];
    float v0 = fmaxf(a0 * inv + bflo(zv.x), 0.f) + bflo(rv.x);
    float v1 = fmaxf(a1 * inv + bfhi(zv.x), 0.f) + bfhi(rv.x);
    float v2 = fmaxf(a2 * inv + bflo(zv.y), 0.f) + bflo(rv.y);
    float v3 = fmaxf(a3 * inv + bfhi(zv.y), 0.f) + bfhi(rv.y);
    uint2 o;
    o.x = (uint32_t)f2bf(v0) | ((uint32_t)f2bf(v1) << 16);
    o.y = (uint32_t)f2bf(v2) | ((uint32_t)f2bf(v3) << 16);
    hb_out[(size_t)wid * 32 + sub] = o;
  }
}

// ------------- final aggregation + log_softmax (half-wave, u32 loads, 2 dims/lane) -------------
__global__ __launch_bounds__(256) void agg_out(const uint32_t* __restrict__ yb2, const float* __restrict__ z2,
                                               const uint16_t* __restrict__ colx, const int* __restrict__ rowp,
                                               float* __restrict__ out){
  int wid = blockIdx.x * 4 + (threadIdx.x >> 6);
  if (wid >= NN) return;
  int lane = threadIdx.x & 63;
  int half = lane >> 5, sub = lane & 31;
  int e0 = rowp[wid], e1 = rowp[wid + 1];
  float a0 = 0.f, a1 = 0.f;
  int e = e0 + half;
  for (; e + 6 < e1; e += 8){
    uint32_t v0 = yb2[(size_t)colx[e]     * 32 + sub];
    uint32_t v1 = yb2[(size_t)colx[e + 2] * 32 + sub];
    uint32_t v2 = yb2[(size_t)colx[e + 4] * 32 + sub];
    uint32_t v3 = yb2[(size_t)colx[e + 6] * 32 + sub];
    a0 += bflo(v0) + bflo(v1) + bflo(v2) + bflo(v3);
    a1 += bfhi(v0) + bfhi(v1) + bfhi(v2) + bfhi(v3);
  }
  for (; e < e1; e += 2){
    uint32_t v = yb2[(size_t)colx[e] * 32 + sub];
    a0 += bflo(v); a1 += bfhi(v);
  }
  a0 += __shfl_xor(a0, 32, 64);
  a1 += __shfl_xor(a1, 32, 64);
  int deg = e1 - e0;
  float inv = deg > 0 ? 1.f / (float)deg : 0.f;
  float2 zv = ((const float2*)z2)[(size_t)wid * 32 + sub];
  float v0 = a0 * inv + zv.x;
  float v1 = a1 * inv + zv.y;
  // softmax over 64 dims: 2 per lane across 32 lanes (both halves hold identical data)
  float mx = fmaxf(v0, v1);
  #pragma unroll
  for (int off = 16; off; off >>= 1) mx = fmaxf(mx, __shfl_xor(mx, off, 64));
  float sm = __expf(v0 - mx) + __expf(v1 - mx);
  #pragma unroll
  for (int off = 16; off; off >>= 1) sm += __shfl_xor(sm, off, 64);
  if (half == 0){
    float ls = __logf(sm);
    float2 o = make_float2((v0 - mx) - ls, (v1 - mx) - ls);
    ((float2*)out)[(size_t)wid * 32 + sub] = o;
  }
}

extern "C" void kernel_launch(void* const* d_in, const int* in_sizes, int n_in,
                              void* d_out, int out_size, void* d_ws, size_t ws_size,
                              hipStream_t stream){
  const float* x    = (const float*)d_in[0];
  const int*   ei   = (const int*)d_in[1];
  const float* w_in = (const float*)d_in[2];
  const float* b_in = (const float*)d_in[3];
  const float* w_l0 = (const float*)d_in[4];
  const float* w_r0 = (const float*)d_in[5];
  const float* b0   = (const float*)d_in[6];
  const float* w_l1 = (const float*)d_in[7];
  const float* w_r1 = (const float*)d_in[8];
  const float* b1   = (const float*)d_in[9];
  const float* w_l2 = (const float*)d_in[10];
  const float* w_r2 = (const float*)d_in[11];
  const float* b2   = (const float*)d_in[12];
  float* out = (float*)d_out;

  char* ws = (char*)d_ws;
  size_t off = 0;
  auto take = [&](size_t bytes) -> char* {
    char* p = ws + off;
    off = (off + bytes + 1023) & ~(size_t)1023;
    return p;
  };
  uint16_t* xb   = (uint16_t*)take((size_t)NN * 128 * 2);   // bf16(x)
  uint16_t* hb   = (uint16_t*)take((size_t)NN * 128 * 2);   // agg outputs
  uint16_t* resb = (uint16_t*)take((size_t)NN * 128 * 2);   // 0.2*inp
  uint16_t* y0   = (uint16_t*)take((size_t)NN * 128 * 2);   // y (reused each conv)
  uint16_t* z0   = (uint16_t*)take((size_t)NN * 128 * 2);   // z (reused; fp32 z2 at end)
  uint32_t* pairs = (uint32_t*)take((size_t)NE * 4);
  uint16_t* colx  = (uint16_t*)take((size_t)NE * 2);
  int* histG    = (int*)take((size_t)NBIN * ABLK * 4);
  int* binStart = (int*)take((size_t)(NBIN + 1) * 4);
  int* rowp     = (int*)take((size_t)(NN + 1) * 4);
  uint16_t* BpIn = (uint16_t*)take(128 * 128 * 2);
  uint16_t* Bp0  = (uint16_t*)take(128 * 256 * 2);
  uint16_t* Bp1  = (uint16_t*)take(128 * 256 * 2);
  uint16_t* Bp2  = (uint16_t*)take(128 * 128 * 2);
  uint16_t* y2 = y0;
  float*    z2 = (float*)z0;
  (void)ws_size; (void)in_sizes; (void)n_in; (void)out_size;

  // fused: cvt (x -> bf16 into xb) + bucket histogram + all weight packs
  k_prep<<<B_CVT + B_HIST + B_PIN + B_P0 + B_P1 + B_P2, 256, 0, stream>>>(
      x, (uint2*)xb, ei, histG, w_in, w_l0, w_r0, w_l1, w_r1, w_l2, w_r2, BpIn, Bp0, Bp1, Bp2);

  // CSR build
  k_scanG<<<1, 256, 0, stream>>>(histG, binStart);
  k_bin<<<ABLK, 256, 0, stream>>>(ei, histG, pairs);
  k_csr<<<NBIN, 256, 0, stream>>>(pairs, binStart, rowp, colx);

  // lin_in + conv0 gemm (fused dense): xb -> resb, y0, z0
  k_lin0<<<NN / 16, 256, 0, stream>>>(xb, BpIn, b_in, Bp0, b0, resb, y0, z0);

  // conv0 agg: y0,z0,res -> hb
  agg_mid<<<NN / 4, 256, 0, stream>>>((const uint2*)y0, (const uint2*)z0, (const uint2*)resb,
                                      colx, rowp, (uint2*)hb);
  // conv1 gemm: hb -> y0, z0
  k_gemm<4, 1><<<1024, 256, 0, stream>>>(hb, Bp1, b1, y0, z0, nullptr);

  // conv1 agg: y0,z0,res -> hb
  agg_mid<<<NN / 4, 256, 0, stream>>>((const uint2*)y0, (const uint2*)z0, (const uint2*)resb,
                                      colx, rowp, (uint2*)hb);
  // conv2 gemm: hb -> y2(bf16 64c), z2(fp32 64c)
  k_gemm<2, 2><<<1024, 256, 0, stream>>>(hb, Bp2, b2, y2, nullptr, z2);

  // conv2 agg + log_softmax
  agg_out<<<NN / 4, 256, 0, stream>>>((const uint32_t*)y2, z2, colx, rowp, out);
}

// Round 9
// 300.930 us; speedup vs baseline: 1.3424x; 1.0222x over previous
//
#include <hip/hip_runtime.h>
#include <stdint.h>

#define NN 50000
#define NE 800000
#define NBIN 196   // dst buckets of 256 nodes (dst >> 8)
#define ABLK 196   // blocks in hist/bin passes
#define EPB 4082   // edges per block: 196*4082 >= NE
#define BCAP 6144  // per-bucket LDS capacity (avg 4096)

typedef __attribute__((ext_vector_type(8))) short short8;
typedef __attribute__((ext_vector_type(4))) float floatx4;

__device__ __forceinline__ uint16_t f2bf(float f){
  union { float f; uint32_t u; } c; c.f = f;
  uint32_t u = c.u + 0x7FFFu + ((c.u >> 16) & 1u);
  return (uint16_t)(u >> 16);
}
__device__ __forceinline__ float bflo(uint32_t v){
  union { uint32_t u; float f; } c; c.u = v << 16; return c.f;
}
__device__ __forceinline__ float bfhi(uint32_t v){
  union { uint32_t u; float f; } c; c.u = v & 0xFFFF0000u; return c.f;
}

// ---------------- fused preprocessing: cvt + hist + weight packs ----------------
#define B_CVT 6250   // NN*128/4 / 256
#define B_HIST ABLK
#define B_PIN 64
#define B_P0  128
#define B_P1  128
#define B_P2  64

__device__ __forceinline__ void pack_one(int idx, const float* __restrict__ wl,
                                         const float* __restrict__ wr,
                                         uint16_t* __restrict__ bp,
                                         int ncolL, int ncolR, int NT){
  int j = idx & 7, lane = (idx >> 3) & 63, rest = idx >> 9;
  int nt = rest % NT, kt = rest / NT;
  int k = kt * 32 + ((lane >> 4) << 3) + j;
  int n = nt * 16 + (lane & 15);
  float v = (n < ncolL) ? wl[k * ncolL + n] : wr[k * ncolR + (n - ncolL)];
  bp[idx] = f2bf(v);
}

__global__ __launch_bounds__(256) void k_prep(const float* __restrict__ x, uint2* __restrict__ xb,
                                              const int* __restrict__ ei, int* __restrict__ histG,
                                              const float* __restrict__ w_in,
                                              const float* __restrict__ w_l0, const float* __restrict__ w_r0,
                                              const float* __restrict__ w_l1, const float* __restrict__ w_r1,
                                              const float* __restrict__ w_l2, const float* __restrict__ w_r2,
                                              uint16_t* __restrict__ bpIn, uint16_t* __restrict__ bp0,
                                              uint16_t* __restrict__ bp1, uint16_t* __restrict__ bp2){
  __shared__ int hsh[NBIN];
  int b = blockIdx.x;
  if (b < B_CVT){
    int i = b * 256 + threadIdx.x;
    if (i < NN * 128 / 4){
      float4 v = ((const float4*)x)[i];
      uint32_t lo = (uint32_t)f2bf(v.x) | ((uint32_t)f2bf(v.y) << 16);
      uint32_t hi = (uint32_t)f2bf(v.z) | ((uint32_t)f2bf(v.w) << 16);
      xb[i] = make_uint2(lo, hi);
    }
    return;
  }
  b -= B_CVT;
  if (b < B_HIST){
    for (int i = threadIdx.x; i < NBIN; i += 256) hsh[i] = 0;
    __syncthreads();
    int base = b * EPB;
    for (int k = threadIdx.x; k < EPB; k += 256){
      int e = base + k;
      if (e < NE) atomicAdd(&hsh[ei[NE + e] >> 8], 1);
    }
    __syncthreads();
    for (int i = threadIdx.x; i < NBIN; i += 256) histG[b * NBIN + i] = hsh[i];
    return;
  }
  b -= B_HIST;
  if (b < B_PIN){ pack_one(b * 256 + threadIdx.x, w_in, w_in, bpIn, 128, 0, 8); return; }
  b -= B_PIN;
  if (b < B_P0){ pack_one(b * 256 + threadIdx.x, w_l0, w_r0, bp0, 128, 128, 16); return; }
  b -= B_P0;
  if (b < B_P1){ pack_one(b * 256 + threadIdx.x, w_l1, w_r1, bp1, 128, 128, 16); return; }
  b -= B_P1;
  pack_one(b * 256 + threadIdx.x, w_l2, w_r2, bp2, 64, 64, 8);
}

// ---------------- pass A2: scan (coalesced [blk][bin] layout) ----------------
__global__ __launch_bounds__(256) void k_scanG(int* __restrict__ histG, int* __restrict__ binStart){
  __shared__ int s[256];
  int t = threadIdx.x;
  int tot = 0;
  if (t < NBIN){
    for (int b = 0; b < ABLK; ++b){
      int v = histG[b * NBIN + t];
      histG[b * NBIN + t] = tot;
      tot += v;
    }
  }
  s[t] = (t < NBIN) ? tot : 0;
  __syncthreads();
  #pragma unroll
  for (int off = 1; off < 256; off <<= 1){
    int u = (t >= off) ? s[t - off] : 0;
    __syncthreads();
    s[t] += u;
    __syncthreads();
  }
  int excl = s[t] - ((t < NBIN) ? tot : 0);
  if (t < NBIN){
    binStart[t] = excl;
    for (int b = 0; b < ABLK; ++b) histG[b * NBIN + t] += excl;
  }
  if (t == 0) binStart[NBIN] = NE;
}

// ---------------- pass A3: LDS bin-sort, contiguous-run writes ----------------
__global__ __launch_bounds__(256) void k_bin(const int* __restrict__ ei, const int* __restrict__ histG,
                                             uint32_t* __restrict__ pairs){
  __shared__ int h[NBIN], loc[NBIN], cur[NBIN], gof[NBIN];
  __shared__ int sc[256];
  __shared__ uint32_t st[EPB];
  int t = threadIdx.x;
  int base = blockIdx.x * EPB;
  for (int i = t; i < NBIN; i += 256) h[i] = 0;
  __syncthreads();
  for (int k = t; k < EPB; k += 256){
    int e = base + k;
    if (e < NE) atomicAdd(&h[ei[NE + e] >> 8], 1);
  }
  __syncthreads();
  int cv = (t < NBIN) ? h[t] : 0;
  sc[t] = cv;
  __syncthreads();
  #pragma unroll
  for (int off = 1; off < 256; off <<= 1){
    int u = (t >= off) ? sc[t - off] : 0;
    __syncthreads();
    sc[t] += u;
    __syncthreads();
  }
  if (t < NBIN){
    int excl = sc[t] - cv;
    loc[t] = excl;
    cur[t] = excl;
    gof[t] = histG[blockIdx.x * NBIN + t];
  }
  __syncthreads();
  for (int k = t; k < EPB; k += 256){
    int e = base + k;
    if (e < NE){
      int d = ei[NE + e];
      int s0 = ei[e];
      int pos = atomicAdd(&cur[d >> 8], 1);
      st[pos] = (uint32_t)s0 | ((uint32_t)d << 16);
    }
  }
  __syncthreads();
  int cnt = min(EPB, NE - base);
  for (int k = t; k < cnt; k += 256){
    uint32_t v = st[k];
    int bin = (int)(v >> 24);
    pairs[gof[bin] + (k - loc[bin])] = v;
  }
}

// ---------------- pass B: per-bucket counting sort -> rowp + colx(u16) ----------------
__global__ __launch_bounds__(256) void k_csr(const uint32_t* __restrict__ pairs, const int* __restrict__ binStart,
                                             int* __restrict__ rowp, uint16_t* __restrict__ colx){
  __shared__ uint32_t pl[BCAP];
  __shared__ uint16_t stg[BCAP];
  __shared__ int h[256], sc[256];
  int i = blockIdx.x, t = threadIdx.x;
  int p0 = binStart[i], p1 = binStart[i + 1];
  int cnt = min(p1 - p0, BCAP);
  for (int k = t; k < cnt; k += 256) pl[k] = pairs[p0 + k];
  h[t] = 0;
  __syncthreads();
  for (int k = t; k < cnt; k += 256) atomicAdd(&h[(pl[k] >> 16) & 255], 1);
  __syncthreads();
  int cv = h[t];
  sc[t] = cv;
  __syncthreads();
  #pragma unroll
  for (int off = 1; off < 256; off <<= 1){
    int u = (t >= off) ? sc[t - off] : 0;
    __syncthreads();
    sc[t] += u;
    __syncthreads();
  }
  int excl = sc[t] - cv;
  int n0 = i << 8;
  int nc = min(256, NN - n0);
  if (t < nc) rowp[n0 + t] = p0 + excl;
  if (i == NBIN - 1 && t == 0) rowp[NN] = NE;
  h[t] = excl;   // becomes cursor
  __syncthreads();
  for (int k = t; k < cnt; k += 256){
    uint32_t v = pl[k];
    int pos = atomicAdd(&h[(v >> 16) & 255], 1);
    stg[pos] = (uint16_t)(v & 0xFFFFu);
  }
  __syncthreads();
  for (int k = t; k < cnt; k += 256) colx[p0 + k] = stg[k];
}

// ------------- fused lin_in + conv0 GEMM -------------
__global__ __launch_bounds__(256) void k_lin0(const uint16_t* __restrict__ xb,
                                              const uint16_t* __restrict__ BpIn, const float* __restrict__ b_in,
                                              const uint16_t* __restrict__ Bp0, const float* __restrict__ b0,
                                              uint16_t* __restrict__ resb, uint16_t* __restrict__ y0,
                                              uint16_t* __restrict__ z0){
  __shared__ uint16_t ash[16 * 136];
  int lane = threadIdx.x & 63, wave = threadIdx.x >> 6;
  short8 bIn[4][2], bC0[4][4];
  #pragma unroll
  for (int kt = 0; kt < 4; ++kt){
    #pragma unroll
    for (int n = 0; n < 2; ++n)
      bIn[kt][n] = *(const short8*)(BpIn + (size_t)((kt * 8 + wave * 2 + n) * 64 + lane) * 8);
    #pragma unroll
    for (int n = 0; n < 4; ++n)
      bC0[kt][n] = *(const short8*)(Bp0 + (size_t)((kt * 16 + wave * 4 + n) * 64 + lane) * 8);
  }
  int m = lane & 15, quad = lane >> 4;
  int r0 = blockIdx.x * 16;
  const uint16_t* arow = xb + (size_t)(r0 + m) * 128 + quad * 8;
  short8 af[4];
  #pragma unroll
  for (int kt = 0; kt < 4; ++kt) af[kt] = *(const short8*)(arow + kt * 32);
  floatx4 accH[2];
  #pragma unroll
  for (int n = 0; n < 2; ++n) accH[n] = (floatx4){0.f, 0.f, 0.f, 0.f};
  #pragma unroll
  for (int kt = 0; kt < 4; ++kt)
    #pragma unroll
    for (int n = 0; n < 2; ++n)
      accH[n] = __builtin_amdgcn_mfma_f32_16x16x32_bf16(af[kt], bIn[kt][n], accH[n], 0, 0, 0);
  int rbase = r0 + quad * 4;
  #pragma unroll
  for (int n = 0; n < 2; ++n){
    int c = (wave * 2 + n) * 16 + m;
    float bi = b_in[c];
    #pragma unroll
    for (int i = 0; i < 4; ++i){
      float hh = accH[n][i] + bi;
      int row = rbase + i;
      resb[(size_t)row * 128 + c] = f2bf(0.2f * hh);
      ash[(quad * 4 + i) * 136 + c] = f2bf(fmaxf(hh, 0.f));
    }
  }
  __syncthreads();
  short8 af2[4];
  #pragma unroll
  for (int kt = 0; kt < 4; ++kt)
    af2[kt] = *(const short8*)&ash[m * 136 + quad * 8 + kt * 32];
  floatx4 acc[4];
  #pragma unroll
  for (int n = 0; n < 4; ++n) acc[n] = (floatx4){0.f, 0.f, 0.f, 0.f};
  #pragma unroll
  for (int kt = 0; kt < 4; ++kt)
    #pragma unroll
    for (int n = 0; n < 4; ++n)
      acc[n] = __builtin_amdgcn_mfma_f32_16x16x32_bf16(af2[kt], bC0[kt][n], acc[n], 0, 0, 0);
  #pragma unroll
  for (int n = 0; n < 4; ++n){
    int c = (wave * 4 + n) * 16 + m;
    #pragma unroll
    for (int i = 0; i < 4; ++i){
      float v = acc[n][i];
      int row = rbase + i;
      if (c < 128) y0[(size_t)row * 128 + c] = f2bf(v);
      else         z0[(size_t)row * 128 + (c - 128)] = f2bf(v + b0[c - 128]);
    }
  }
}

// ------------- GEMM: A[N,128]bf16 @ Bp[128, NCOL] -> epilogue -------------
template<int NTW, int MODE>
__global__ __launch_bounds__(256) void k_gemm(const uint16_t* __restrict__ A, const uint16_t* __restrict__ Bp,
                                              const float* __restrict__ bias,
                                              uint16_t* __restrict__ o0, uint16_t* __restrict__ o1,
                                              float* __restrict__ o2){
  const int NTT = 4 * NTW;
  int lane = threadIdx.x & 63;
  int wave = threadIdx.x >> 6;
  short8 bfrag[4][NTW];
  #pragma unroll
  for (int kt = 0; kt < 4; ++kt)
    #pragma unroll
    for (int n = 0; n < NTW; ++n)
      bfrag[kt][n] = *(const short8*)(Bp + (size_t)((kt * NTT + wave * NTW + n) * 64 + lane) * 8);

  int m = lane & 15, quad = lane >> 4;
  const int nrt = NN / 16;
  for (int rt = blockIdx.x; rt < nrt; rt += gridDim.x){
    int r0 = rt * 16;
    const uint16_t* arow = A + (size_t)(r0 + m) * 128 + quad * 8;
    short8 af[4];
    #pragma unroll
    for (int kt = 0; kt < 4; ++kt) af[kt] = *(const short8*)(arow + kt * 32);
    floatx4 acc[NTW];
    #pragma unroll
    for (int n = 0; n < NTW; ++n) acc[n] = (floatx4){0.f, 0.f, 0.f, 0.f};
    #pragma unroll
    for (int kt = 0; kt < 4; ++kt)
      #pragma unroll
      for (int n = 0; n < NTW; ++n)
        acc[n] = __builtin_amdgcn_mfma_f32_16x16x32_bf16(af[kt], bfrag[kt][n], acc[n], 0, 0, 0);

    int rbase = r0 + quad * 4;
    #pragma unroll
    for (int n = 0; n < NTW; ++n){
      int c = (wave * NTW + n) * 16 + m;
      #pragma unroll
      for (int i = 0; i < 4; ++i){
        float v = acc[n][i];
        int row = rbase + i;
        if (MODE == 1){
          if (c < 128) o0[(size_t)row * 128 + c] = f2bf(v);
          else         o1[(size_t)row * 128 + (c - 128)] = f2bf(v + bias[c - 128]);
        } else {
          if (c < 64) o0[(size_t)row * 64 + c] = f2bf(v);
          else        o2[(size_t)row * 64 + (c - 64)] = v + bias[c - 64];
        }
      }
    }
  }
}

// ------------- aggregation: one wave per node; quarter-wave (16 lanes x uint4) per edge -------------
// lane = 16*q + sub; quarter q processes edges e0+q, e0+q+4, ...; sub covers dims 8*sub..8*sub+7
__global__ __launch_bounds__(256) void agg_mid(const uint4* __restrict__ yb, const uint4* __restrict__ zb,
                                               const uint4* __restrict__ resb,
                                               const uint16_t* __restrict__ colx, const int* __restrict__ rowp,
                                               uint4* __restrict__ hb_out){
  int wid = blockIdx.x * 4 + (threadIdx.x >> 6);
  if (wid >= NN) return;
  int lane = threadIdx.x & 63;
  int q = lane >> 4, sub = lane & 15;
  int e0 = rowp[wid], e1 = rowp[wid + 1];
  float a0 = 0.f, a1 = 0.f, a2 = 0.f, a3 = 0.f, a4 = 0.f, a5 = 0.f, a6 = 0.f, a7 = 0.f;
  int e = e0 + q;
  for (; e + 12 < e1; e += 16){
    uint4 v0 = yb[(size_t)colx[e]      * 16 + sub];
    uint4 v1 = yb[(size_t)colx[e + 4]  * 16 + sub];
    uint4 v2 = yb[(size_t)colx[e + 8]  * 16 + sub];
    uint4 v3 = yb[(size_t)colx[e + 12] * 16 + sub];
    a0 += bflo(v0.x) + bflo(v1.x) + bflo(v2.x) + bflo(v3.x);
    a1 += bfhi(v0.x) + bfhi(v1.x) + bfhi(v2.x) + bfhi(v3.x);
    a2 += bflo(v0.y) + bflo(v1.y) + bflo(v2.y) + bflo(v3.y);
    a3 += bfhi(v0.y) + bfhi(v1.y) + bfhi(v2.y) + bfhi(v3.y);
    a4 += bflo(v0.z) + bflo(v1.z) + bflo(v2.z) + bflo(v3.z);
    a5 += bfhi(v0.z) + bfhi(v1.z) + bfhi(v2.z) + bfhi(v3.z);
    a6 += bflo(v0.w) + bflo(v1.w) + bflo(v2.w) + bflo(v3.w);
    a7 += bfhi(v0.w) + bfhi(v1.w) + bfhi(v2.w) + bfhi(v3.w);
  }
  for (; e < e1; e += 4){
    uint4 v = yb[(size_t)colx[e] * 16 + sub];
    a0 += bflo(v.x); a1 += bfhi(v.x); a2 += bflo(v.y); a3 += bfhi(v.y);
    a4 += bflo(v.z); a5 += bfhi(v.z); a6 += bflo(v.w); a7 += bfhi(v.w);
  }
  // combine the four quarters (same node, same dims)
  #pragma unroll
  for (int off = 16; off < 64; off <<= 1){
    a0 += __shfl_xor(a0, off, 64);
    a1 += __shfl_xor(a1, off, 64);
    a2 += __shfl_xor(a2, off, 64);
    a3 += __shfl_xor(a3, off, 64);
    a4 += __shfl_xor(a4, off, 64);
    a5 += __shfl_xor(a5, off, 64);
    a6 += __shfl_xor(a6, off, 64);
    a7 += __shfl_xor(a7, off, 64);
  }
  int deg = e1 - e0;
  float inv = deg > 0 ? 1.f / (float)deg : 0.f;
  if (q == 0){
    uint4 zv = zb[(size_t)wid * 16 + sub];
    uint4 rv = resb[(size_t)wid * 16 + sub];
    float w0 = fmaxf(a0 * inv + bflo(zv.x), 0.f) + bflo(rv.x);
    float w1 = fmaxf(a1 * inv + bfhi(zv.x), 0.f) + bfhi(rv.x);
    float w2 = fmaxf(a2 * inv + bflo(zv.y), 0.f) + bflo(rv.y);
    float w3 = fmaxf(a3 * inv + bfhi(zv.y), 0.f) + bfhi(rv.y);
    float w4 = fmaxf(a4 * inv + bflo(zv.z), 0.f) + bflo(rv.z);
    float w5 = fmaxf(a5 * inv + bfhi(zv.z), 0.f) + bfhi(rv.z);
    float w6 = fmaxf(a6 * inv + bflo(zv.w), 0.f) + bflo(rv.w);
    float w7 = fmaxf(a7 * inv + bfhi(zv.w), 0.f) + bfhi(rv.w);
    uint4 o;
    o.x = (uint32_t)f2bf(w0) | ((uint32_t)f2bf(w1) << 16);
    o.y = (uint32_t)f2bf(w2) | ((uint32_t)f2bf(w3) << 16);
    o.z = (uint32_t)f2bf(w4) | ((uint32_t)f2bf(w5) << 16);
    o.w = (uint32_t)f2bf(w6) | ((uint32_t)f2bf(w7) << 16);
    hb_out[(size_t)wid * 16 + sub] = o;
  }
}

// ------------- final aggregation + log_softmax (quarter-wave, uint2 loads, 4 dims/lane) -------------
__global__ __launch_bounds__(256) void agg_out(const uint2* __restrict__ yb2, const float* __restrict__ z2,
                                               const uint16_t* __restrict__ colx, const int* __restrict__ rowp,
                                               float* __restrict__ out){
  int wid = blockIdx.x * 4 + (threadIdx.x >> 6);
  if (wid >= NN) return;
  int lane = threadIdx.x & 63;
  int q = lane >> 4, sub = lane & 15;
  int e0 = rowp[wid], e1 = rowp[wid + 1];
  float a0 = 0.f, a1 = 0.f, a2 = 0.f, a3 = 0.f;
  int e = e0 + q;
  for (; e + 12 < e1; e += 16){
    uint2 v0 = yb2[(size_t)colx[e]      * 16 + sub];
    uint2 v1 = yb2[(size_t)colx[e + 4]  * 16 + sub];
    uint2 v2 = yb2[(size_t)colx[e + 8]  * 16 + sub];
    uint2 v3 = yb2[(size_t)colx[e + 12] * 16 + sub];
    a0 += bflo(v0.x) + bflo(v1.x) + bflo(v2.x) + bflo(v3.x);
    a1 += bfhi(v0.x) + bfhi(v1.x) + bfhi(v2.x) + bfhi(v3.x);
    a2 += bflo(v0.y) + bflo(v1.y) + bflo(v2.y) + bflo(v3.y);
    a3 += bfhi(v0.y) + bfhi(v1.y) + bfhi(v2.y) + bfhi(v3.y);
  }
  for (; e < e1; e += 4){
    uint2 v = yb2[(size_t)colx[e] * 16 + sub];
    a0 += bflo(v.x); a1 += bfhi(v.x); a2 += bflo(v.y); a3 += bfhi(v.y);
  }
  #pragma unroll
  for (int off = 16; off < 64; off <<= 1){
    a0 += __shfl_xor(a0, off, 64);
    a1 += __shfl_xor(a1, off, 64);
    a2 += __shfl_xor(a2, off, 64);
    a3 += __shfl_xor(a3, off, 64);
  }
  int deg = e1 - e0;
  float inv = deg > 0 ? 1.f / (float)deg : 0.f;
  float4 zv = ((const float4*)z2)[(size_t)wid * 16 + sub];
  float v0 = a0 * inv + zv.x;
  float v1 = a1 * inv + zv.y;
  float v2 = a2 * inv + zv.z;
  float v3 = a3 * inv + zv.w;
  // softmax over 64 dims: 4 per lane across the 16 subs (all quarters identical)
  float mx = fmaxf(fmaxf(v0, v1), fmaxf(v2, v3));
  #pragma unroll
  for (int off = 1; off < 16; off <<= 1) mx = fmaxf(mx, __shfl_xor(mx, off, 64));
  float sm = __expf(v0 - mx) + __expf(v1 - mx) + __expf(v2 - mx) + __expf(v3 - mx);
  #pragma unroll
  for (int off = 1; off < 16; off <<= 1) sm += __shfl_xor(sm, off, 64);
  if (q == 0){
    float ls = __logf(sm);
    float4 o = make_float4((v0 - mx) - ls, (v1 - mx) - ls, (v2 - mx) - ls, (v3 - mx) - ls);
    ((float4*)out)[(size_t)wid * 16 + sub] = o;
  }
}

extern "C" void kernel_launch(void* const* d_in, const int* in_sizes, int n_in,
                              void* d_out, int out_size, void* d_ws, size_t ws_size,
                              hipStream_t stream){
  const float* x    = (const float*)d_in[0];
  const int*   ei   = (const int*)d_in[1];
  const float* w_in = (const float*)d_in[2];
  const float* b_in = (const float*)d_in[3];
  const float* w_l0 = (const float*)d_in[4];
  const float* w_r0 = (const float*)d_in[5];
  const float* b0   = (const float*)d_in[6];
  const float* w_l1 = (const float*)d_in[7];
  const float* w_r1 = (const float*)d_in[8];
  const float* b1   = (const float*)d_in[9];
  const float* w_l2 = (const float*)d_in[10];
  const float* w_r2 = (const float*)d_in[11];
  const float* b2   = (const float*)d_in[12];
  float* out = (float*)d_out;

  char* ws = (char*)d_ws;
  size_t off = 0;
  auto take = [&](size_t bytes) -> char* {
    char* p = ws + off;
    off = (off + bytes + 1023) & ~(size_t)1023;
    return p;
  };
  uint16_t* xb   = (uint16_t*)take((size_t)NN * 128 * 2);   // bf16(x)
  uint16_t* hb   = (uint16_t*)take((size_t)NN * 128 * 2);   // agg outputs
  uint16_t* resb = (uint16_t*)take((size_t)NN * 128 * 2);   // 0.2*inp
  uint16_t* y0   = (uint16_t*)take((size_t)NN * 128 * 2);   // y (reused each conv)
  uint16_t* z0   = (uint16_t*)take((size_t)NN * 128 * 2);   // z (reused; fp32 z2 at end)
  uint32_t* pairs = (uint32_t*)take((size_t)NE * 4);
  uint16_t* colx  = (uint16_t*)take((size_t)NE * 2);
  int* histG    = (int*)take((size_t)NBIN * ABLK * 4);
  int* binStart = (int*)take((size_t)(NBIN + 1) * 4);
  int* rowp     = (int*)take((size_t)(NN + 1) * 4);
  uint16_t* BpIn = (uint16_t*)take(128 * 128 * 2);
  uint16_t* Bp0  = (uint16_t*)take(128 * 256 * 2);
  uint16_t* Bp1  = (uint16_t*)take(128 * 256 * 2);
  uint16_t* Bp2  = (uint16_t*)take(128 * 128 * 2);
  uint16_t* y2 = y0;
  float*    z2 = (float*)z0;
  (void)ws_size; (void)in_sizes; (void)n_in; (void)out_size;

  // fused: cvt (x -> bf16 into xb) + bucket histogram + all weight packs
  k_prep<<<B_CVT + B_HIST + B_PIN + B_P0 + B_P1 + B_P2, 256, 0, stream>>>(
      x, (uint2*)xb, ei, histG, w_in, w_l0, w_r0, w_l1, w_r1, w_l2, w_r2, BpIn, Bp0, Bp1, Bp2);

  // CSR build
  k_scanG<<<1, 256, 0, stream>>>(histG, binStart);
  k_bin<<<ABLK, 256, 0, stream>>>(ei, histG, pairs);
  k_csr<<<NBIN, 256, 0, stream>>>(pairs, binStart, rowp, colx);

  // lin_in + conv0 gemm (fused dense): xb -> resb, y0, z0
  k_lin0<<<NN / 16, 256, 0, stream>>>(xb, BpIn, b_in, Bp0, b0, resb, y0, z0);

  // conv0 agg: y0,z0,res -> hb
  agg_mid<<<NN / 4, 256, 0, stream>>>((const uint4*)y0, (const uint4*)z0, (const uint4*)resb,
                                      colx, rowp, (uint4*)hb);
  // conv1 gemm: hb -> y0, z0
  k_gemm<4, 1><<<1024, 256, 0, stream>>>(hb, Bp1, b1, y0, z0, nullptr);

  // conv1 agg: y0,z0,res -> hb
  agg_mid<<<NN / 4, 256, 0, stream>>>((const uint4*)y0, (const uint4*)z0, (const uint4*)resb,
                                      colx, rowp, (uint4*)hb);
  // conv2 gemm: hb -> y2(bf16 64c), z2(fp32 64c)
  k_gemm<2, 2><<<1024, 256, 0, stream>>>(hb, Bp2, b2, y2, nullptr, z2);

  // conv2 agg + log_softmax
  agg_out<<<NN / 4, 256, 0, stream>>>((const uint2*)y2, z2, colx, rowp, out);
}

// Round 10
// 289.447 us; speedup vs baseline: 1.3957x; 1.0397x over previous
//
#include <hip/hip_runtime.h>
#include <stdint.h>

#define NN 50000
#define NE 800000
#define NBIN 196   // dst buckets of 256 nodes (dst >> 8)
#define ABLK 196   // blocks in hist/bin passes
#define EPB 4082   // edges per block: 196*4082 >= NE
#define BCAP 6144  // per-bucket LDS capacity (avg 4096)

typedef __attribute__((ext_vector_type(8))) short short8;
typedef __attribute__((ext_vector_type(4))) float floatx4;

__device__ __forceinline__ uint16_t f2bf(float f){
  union { float f; uint32_t u; } c; c.f = f;
  uint32_t u = c.u + 0x7FFFu + ((c.u >> 16) & 1u);
  return (uint16_t)(u >> 16);
}
__device__ __forceinline__ float bflo(uint32_t v){
  union { uint32_t u; float f; } c; c.u = v << 16; return c.f;
}
__device__ __forceinline__ float bfhi(uint32_t v){
  union { uint32_t u; float f; } c; c.u = v & 0xFFFF0000u; return c.f;
}

// ---------------- prep: bucket histogram + weight packs (cvt now fused into lin0) ----------------
#define B_HIST ABLK
#define B_PIN 64
#define B_P0  128
#define B_P1  128
#define B_P2  64

__device__ __forceinline__ void pack_one(int idx, const float* __restrict__ wl,
                                         const float* __restrict__ wr,
                                         uint16_t* __restrict__ bp,
                                         int ncolL, int ncolR, int NT){
  int j = idx & 7, lane = (idx >> 3) & 63, rest = idx >> 9;
  int nt = rest % NT, kt = rest / NT;
  int k = kt * 32 + ((lane >> 4) << 3) + j;
  int n = nt * 16 + (lane & 15);
  float v = (n < ncolL) ? wl[k * ncolL + n] : wr[k * ncolR + (n - ncolL)];
  bp[idx] = f2bf(v);
}

__global__ __launch_bounds__(256) void k_prep(const int* __restrict__ ei, int* __restrict__ histG,
                                              const float* __restrict__ w_in,
                                              const float* __restrict__ w_l0, const float* __restrict__ w_r0,
                                              const float* __restrict__ w_l1, const float* __restrict__ w_r1,
                                              const float* __restrict__ w_l2, const float* __restrict__ w_r2,
                                              uint16_t* __restrict__ bpIn, uint16_t* __restrict__ bp0,
                                              uint16_t* __restrict__ bp1, uint16_t* __restrict__ bp2){
  __shared__ int hsh[NBIN];
  int b = blockIdx.x;
  if (b < B_HIST){
    for (int i = threadIdx.x; i < NBIN; i += 256) hsh[i] = 0;
    __syncthreads();
    int base = b * EPB;
    for (int k = threadIdx.x; k < EPB; k += 256){
      int e = base + k;
      if (e < NE) atomicAdd(&hsh[ei[NE + e] >> 8], 1);
    }
    __syncthreads();
    for (int i = threadIdx.x; i < NBIN; i += 256) histG[b * NBIN + i] = hsh[i];
    return;
  }
  b -= B_HIST;
  if (b < B_PIN){ pack_one(b * 256 + threadIdx.x, w_in, w_in, bpIn, 128, 0, 8); return; }
  b -= B_PIN;
  if (b < B_P0){ pack_one(b * 256 + threadIdx.x, w_l0, w_r0, bp0, 128, 128, 16); return; }
  b -= B_P0;
  if (b < B_P1){ pack_one(b * 256 + threadIdx.x, w_l1, w_r1, bp1, 128, 128, 16); return; }
  b -= B_P1;
  pack_one(b * 256 + threadIdx.x, w_l2, w_r2, bp2, 64, 64, 8);
}

// ---------------- scanG: parallel column-sum + 196-bin scan + seed padded cursors ----------------
__global__ __launch_bounds__(256) void k_scanG(const int* __restrict__ histG, int* __restrict__ binStart,
                                               int* __restrict__ binCur){
  __shared__ int s[256];
  int t = threadIdx.x;
  int tot = 0;
  if (t < NBIN){
    #pragma unroll 4
    for (int b = 0; b < ABLK; ++b) tot += histG[b * NBIN + t];   // independent loads, latency-hidden
  }
  s[t] = (t < NBIN) ? tot : 0;
  __syncthreads();
  #pragma unroll
  for (int off = 1; off < 256; off <<= 1){
    int u = (t >= off) ? s[t - off] : 0;
    __syncthreads();
    s[t] += u;
    __syncthreads();
  }
  int excl = s[t] - ((t < NBIN) ? tot : 0);
  if (t < NBIN){
    binStart[t] = excl;
    binCur[t * 16] = excl;   // line-padded cursor (one 64B line per bin)
  }
  if (t == 0) binStart[NBIN] = NE;
}

// ---------------- k_mid: fused [bucket bin-sort (196 blocks)] + [lin_in+conv0 GEMM (3125 blocks)] ----------------
#define B_BIN 196
#define SMSZ 20488   // bin branch: 4*NBIN*4 + 256*4 + EPB*4

__global__ __launch_bounds__(256) void k_mid(const int* __restrict__ ei, int* __restrict__ binCur,
                                             uint32_t* __restrict__ pairs,
                                             const float* __restrict__ x,
                                             const uint16_t* __restrict__ BpIn, const float* __restrict__ b_in,
                                             const uint16_t* __restrict__ Bp0, const float* __restrict__ b0,
                                             uint16_t* __restrict__ resb, uint16_t* __restrict__ y0,
                                             uint16_t* __restrict__ z0){
  __shared__ __align__(16) char smraw[SMSZ];
  int t = threadIdx.x;
  if (blockIdx.x < B_BIN){
    // ---- bucket bin-sort ----
    int* h   = (int*)smraw;
    int* loc = h + NBIN;
    int* cur = loc + NBIN;
    int* gof = cur + NBIN;
    int* sc  = gof + NBIN;
    uint32_t* st = (uint32_t*)(sc + 256);
    int base = blockIdx.x * EPB;
    for (int i = t; i < NBIN; i += 256) h[i] = 0;
    __syncthreads();
    for (int k = t; k < EPB; k += 256){
      int e = base + k;
      if (e < NE) atomicAdd(&h[ei[NE + e] >> 8], 1);
    }
    __syncthreads();
    int cv = (t < NBIN) ? h[t] : 0;
    sc[t] = cv;
    __syncthreads();
    #pragma unroll
    for (int off = 1; off < 256; off <<= 1){
      int u = (t >= off) ? sc[t - off] : 0;
      __syncthreads();
      sc[t] += u;
      __syncthreads();
    }
    if (t < NBIN){
      int excl = sc[t] - cv;
      loc[t] = excl;
      cur[t] = excl;
      if (cv) gof[t] = atomicAdd(&binCur[t * 16], cv);   // reserve run in bucket (order irrelevant)
    }
    __syncthreads();
    for (int k = t; k < EPB; k += 256){
      int e = base + k;
      if (e < NE){
        int d = ei[NE + e];
        int s0 = ei[e];
        int pos = atomicAdd(&cur[d >> 8], 1);
        st[pos] = (uint32_t)s0 | ((uint32_t)d << 16);
      }
    }
    __syncthreads();
    int cnt = min(EPB, NE - base);
    for (int k = t; k < cnt; k += 256){
      uint32_t v = st[k];
      int bin = (int)(v >> 24);
      pairs[gof[bin] + (k - loc[bin])] = v;
    }
    return;
  }
  // ---- lin_in + conv0 GEMM (reads fp32 x directly) ----
  uint16_t* ash = (uint16_t*)smraw;   // 16 x 128, stride 136
  int lane = t & 63, wave = t >> 6;
  short8 bIn[4][2], bC0[4][4];
  #pragma unroll
  for (int kt = 0; kt < 4; ++kt){
    #pragma unroll
    for (int n = 0; n < 2; ++n)
      bIn[kt][n] = *(const short8*)(BpIn + (size_t)((kt * 8 + wave * 2 + n) * 64 + lane) * 8);
    #pragma unroll
    for (int n = 0; n < 4; ++n)
      bC0[kt][n] = *(const short8*)(Bp0 + (size_t)((kt * 16 + wave * 4 + n) * 64 + lane) * 8);
  }
  int m = lane & 15, quad = lane >> 4;
  int r0 = (blockIdx.x - B_BIN) * 16;
  const float* xrow = x + (size_t)(r0 + m) * 128 + quad * 8;
  short8 af[4];
  #pragma unroll
  for (int kt = 0; kt < 4; ++kt){
    float4 p = *(const float4*)(xrow + kt * 32);
    float4 q2 = *(const float4*)(xrow + kt * 32 + 4);
    short8 a;
    a[0] = (short)f2bf(p.x);  a[1] = (short)f2bf(p.y);
    a[2] = (short)f2bf(p.z);  a[3] = (short)f2bf(p.w);
    a[4] = (short)f2bf(q2.x); a[5] = (short)f2bf(q2.y);
    a[6] = (short)f2bf(q2.z); a[7] = (short)f2bf(q2.w);
    af[kt] = a;
  }
  floatx4 accH[2];
  #pragma unroll
  for (int n = 0; n < 2; ++n) accH[n] = (floatx4){0.f, 0.f, 0.f, 0.f};
  #pragma unroll
  for (int kt = 0; kt < 4; ++kt)
    #pragma unroll
    for (int n = 0; n < 2; ++n)
      accH[n] = __builtin_amdgcn_mfma_f32_16x16x32_bf16(af[kt], bIn[kt][n], accH[n], 0, 0, 0);
  int rbase = r0 + quad * 4;
  #pragma unroll
  for (int n = 0; n < 2; ++n){
    int c = (wave * 2 + n) * 16 + m;
    float bi = b_in[c];
    #pragma unroll
    for (int i = 0; i < 4; ++i){
      float hh = accH[n][i] + bi;
      int row = rbase + i;
      resb[(size_t)row * 128 + c] = f2bf(0.2f * hh);
      ash[(quad * 4 + i) * 136 + c] = f2bf(fmaxf(hh, 0.f));
    }
  }
  __syncthreads();
  short8 af2[4];
  #pragma unroll
  for (int kt = 0; kt < 4; ++kt)
    af2[kt] = *(const short8*)&ash[m * 136 + quad * 8 + kt * 32];
  floatx4 acc[4];
  #pragma unroll
  for (int n = 0; n < 4; ++n) acc[n] = (floatx4){0.f, 0.f, 0.f, 0.f};
  #pragma unroll
  for (int kt = 0; kt < 4; ++kt)
    #pragma unroll
    for (int n = 0; n < 4; ++n)
      acc[n] = __builtin_amdgcn_mfma_f32_16x16x32_bf16(af2[kt], bC0[kt][n], acc[n], 0, 0, 0);
  #pragma unroll
  for (int n = 0; n < 4; ++n){
    int c = (wave * 4 + n) * 16 + m;
    #pragma unroll
    for (int i = 0; i < 4; ++i){
      float v = acc[n][i];
      int row = rbase + i;
      if (c < 128) y0[(size_t)row * 128 + c] = f2bf(v);
      else         z0[(size_t)row * 128 + (c - 128)] = f2bf(v + b0[c - 128]);
    }
  }
}

// ---------------- pass B: per-bucket counting sort -> rowp + colx(u16) ----------------
__global__ __launch_bounds__(256) void k_csr(const uint32_t* __restrict__ pairs, const int* __restrict__ binStart,
                                             int* __restrict__ rowp, uint16_t* __restrict__ colx){
  __shared__ uint32_t pl[BCAP];
  __shared__ uint16_t stg[BCAP];
  __shared__ int h[256], sc[256];
  int i = blockIdx.x, t = threadIdx.x;
  int p0 = binStart[i], p1 = binStart[i + 1];
  int cnt = min(p1 - p0, BCAP);
  for (int k = t; k < cnt; k += 256) pl[k] = pairs[p0 + k];
  h[t] = 0;
  __syncthreads();
  for (int k = t; k < cnt; k += 256) atomicAdd(&h[(pl[k] >> 16) & 255], 1);
  __syncthreads();
  int cv = h[t];
  sc[t] = cv;
  __syncthreads();
  #pragma unroll
  for (int off = 1; off < 256; off <<= 1){
    int u = (t >= off) ? sc[t - off] : 0;
    __syncthreads();
    sc[t] += u;
    __syncthreads();
  }
  int excl = sc[t] - cv;
  int n0 = i << 8;
  int nc = min(256, NN - n0);
  if (t < nc) rowp[n0 + t] = p0 + excl;
  if (i == NBIN - 1 && t == 0) rowp[NN] = NE;
  h[t] = excl;   // becomes cursor
  __syncthreads();
  for (int k = t; k < cnt; k += 256){
    uint32_t v = pl[k];
    int pos = atomicAdd(&h[(v >> 16) & 255], 1);
    stg[pos] = (uint16_t)(v & 0xFFFFu);
  }
  __syncthreads();
  for (int k = t; k < cnt; k += 256) colx[p0 + k] = stg[k];
}

// ------------- GEMM: A[N,128]bf16 @ Bp[128, NCOL] -> epilogue -------------
template<int NTW, int MODE>
__global__ __launch_bounds__(256) void k_gemm(const uint16_t* __restrict__ A, const uint16_t* __restrict__ Bp,
                                              const float* __restrict__ bias,
                                              uint16_t* __restrict__ o0, uint16_t* __restrict__ o1,
                                              float* __restrict__ o2){
  const int NTT = 4 * NTW;
  int lane = threadIdx.x & 63;
  int wave = threadIdx.x >> 6;
  short8 bfrag[4][NTW];
  #pragma unroll
  for (int kt = 0; kt < 4; ++kt)
    #pragma unroll
    for (int n = 0; n < NTW; ++n)
      bfrag[kt][n] = *(const short8*)(Bp + (size_t)((kt * NTT + wave * NTW + n) * 64 + lane) * 8);

  int m = lane & 15, quad = lane >> 4;
  const int nrt = NN / 16;
  for (int rt = blockIdx.x; rt < nrt; rt += gridDim.x){
    int r0 = rt * 16;
    const uint16_t* arow = A + (size_t)(r0 + m) * 128 + quad * 8;
    short8 af[4];
    #pragma unroll
    for (int kt = 0; kt < 4; ++kt) af[kt] = *(const short8*)(arow + kt * 32);
    floatx4 acc[NTW];
    #pragma unroll
    for (int n = 0; n < NTW; ++n) acc[n] = (floatx4){0.f, 0.f, 0.f, 0.f};
    #pragma unroll
    for (int kt = 0; kt < 4; ++kt)
      #pragma unroll
      for (int n = 0; n < NTW; ++n)
        acc[n] = __builtin_amdgcn_mfma_f32_16x16x32_bf16(af[kt], bfrag[kt][n], acc[n], 0, 0, 0);

    int rbase = r0 + quad * 4;
    #pragma unroll
    for (int n = 0; n < NTW; ++n){
      int c = (wave * NTW + n) * 16 + m;
      #pragma unroll
      for (int i = 0; i < 4; ++i){
        float v = acc[n][i];
        int row = rbase + i;
        if (MODE == 1){
          if (c < 128) o0[(size_t)row * 128 + c] = f2bf(v);
          else         o1[(size_t)row * 128 + (c - 128)] = f2bf(v + bias[c - 128]);
        } else {
          if (c < 64) o0[(size_t)row * 64 + c] = f2bf(v);
          else        o2[(size_t)row * 64 + (c - 64)] = v + bias[c - 64];
        }
      }
    }
  }
}

// ------------- aggregation: one wave per node; quarter-wave (16 lanes x uint4) per edge -------------
__global__ __launch_bounds__(256) void agg_mid(const uint4* __restrict__ yb, const uint4* __restrict__ zb,
                                               const uint4* __restrict__ resb,
                                               const uint16_t* __restrict__ colx, const int* __restrict__ rowp,
                                               uint4* __restrict__ hb_out){
  int wid = blockIdx.x * 4 + (threadIdx.x >> 6);
  if (wid >= NN) return;
  int lane = threadIdx.x & 63;
  int q = lane >> 4, sub = lane & 15;
  int e0 = rowp[wid], e1 = rowp[wid + 1];
  float a0 = 0.f, a1 = 0.f, a2 = 0.f, a3 = 0.f, a4 = 0.f, a5 = 0.f, a6 = 0.f, a7 = 0.f;
  int e = e0 + q;
  for (; e + 12 < e1; e += 16){
    uint4 v0 = yb[(size_t)colx[e]      * 16 + sub];
    uint4 v1 = yb[(size_t)colx[e + 4]  * 16 + sub];
    uint4 v2 = yb[(size_t)colx[e + 8]  * 16 + sub];
    uint4 v3 = yb[(size_t)colx[e + 12] * 16 + sub];
    a0 += bflo(v0.x) + bflo(v1.x) + bflo(v2.x) + bflo(v3.x);
    a1 += bfhi(v0.x) + bfhi(v1.x) + bfhi(v2.x) + bfhi(v3.x);
    a2 += bflo(v0.y) + bflo(v1.y) + bflo(v2.y) + bflo(v3.y);
    a3 += bfhi(v0.y) + bfhi(v1.y) + bfhi(v2.y) + bfhi(v3.y);
    a4 += bflo(v0.z) + bflo(v1.z) + bflo(v2.z) + bflo(v3.z);
    a5 += bfhi(v0.z) + bfhi(v1.z) + bfhi(v2.z) + bfhi(v3.z);
    a6 += bflo(v0.w) + bflo(v1.w) + bflo(v2.w) + bflo(v3.w);
    a7 += bfhi(v0.w) + bfhi(v1.w) + bfhi(v2.w) + bfhi(v3.w);
  }
  for (; e < e1; e += 4){
    uint4 v = yb[(size_t)colx[e] * 16 + sub];
    a0 += bflo(v.x); a1 += bfhi(v.x); a2 += bflo(v.y); a3 += bfhi(v.y);
    a4 += bflo(v.z); a5 += bfhi(v.z); a6 += bflo(v.w); a7 += bfhi(v.w);
  }
  #pragma unroll
  for (int off = 16; off < 64; off <<= 1){
    a0 += __shfl_xor(a0, off, 64);
    a1 += __shfl_xor(a1, off, 64);
    a2 += __shfl_xor(a2, off, 64);
    a3 += __shfl_xor(a3, off, 64);
    a4 += __shfl_xor(a4, off, 64);
    a5 += __shfl_xor(a5, off, 64);
    a6 += __shfl_xor(a6, off, 64);
    a7 += __shfl_xor(a7, off, 64);
  }
  int deg = e1 - e0;
  float inv = deg > 0 ? 1.f / (float)deg : 0.f;
  if (q == 0){
    uint4 zv = zb[(size_t)wid * 16 + sub];
    uint4 rv = resb[(size_t)wid * 16 + sub];
    float w0 = fmaxf(a0 * inv + bflo(zv.x), 0.f) + bflo(rv.x);
    float w1 = fmaxf(a1 * inv + bfhi(zv.x), 0.f) + bfhi(rv.x);
    float w2 = fmaxf(a2 * inv + bflo(zv.y), 0.f) + bflo(rv.y);
    float w3 = fmaxf(a3 * inv + bfhi(zv.y), 0.f) + bfhi(rv.y);
    float w4 = fmaxf(a4 * inv + bflo(zv.z), 0.f) + bflo(rv.z);
    float w5 = fmaxf(a5 * inv + bfhi(zv.z), 0.f) + bfhi(rv.z);
    float w6 = fmaxf(a6 * inv + bflo(zv.w), 0.f) + bflo(rv.w);
    float w7 = fmaxf(a7 * inv + bfhi(zv.w), 0.f) + bfhi(rv.w);
    uint4 o;
    o.x = (uint32_t)f2bf(w0) | ((uint32_t)f2bf(w1) << 16);
    o.y = (uint32_t)f2bf(w2) | ((uint32_t)f2bf(w3) << 16);
    o.z = (uint32_t)f2bf(w4) | ((uint32_t)f2bf(w5) << 16);
    o.w = (uint32_t)f2bf(w6) | ((uint32_t)f2bf(w7) << 16);
    hb_out[(size_t)wid * 16 + sub] = o;
  }
}

// ------------- final aggregation + log_softmax (quarter-wave, uint2 loads, 4 dims/lane) -------------
__global__ __launch_bounds__(256) void agg_out(const uint2* __restrict__ yb2, const float* __restrict__ z2,
                                               const uint16_t* __restrict__ colx, const int* __restrict__ rowp,
                                               float* __restrict__ out){
  int wid = blockIdx.x * 4 + (threadIdx.x >> 6);
  if (wid >= NN) return;
  int lane = threadIdx.x & 63;
  int q = lane >> 4, sub = lane & 15;
  int e0 = rowp[wid], e1 = rowp[wid + 1];
  float a0 = 0.f, a1 = 0.f, a2 = 0.f, a3 = 0.f;
  int e = e0 + q;
  for (; e + 12 < e1; e += 16){
    uint2 v0 = yb2[(size_t)colx[e]      * 16 + sub];
    uint2 v1 = yb2[(size_t)colx[e + 4]  * 16 + sub];
    uint2 v2 = yb2[(size_t)colx[e + 8]  * 16 + sub];
    uint2 v3 = yb2[(size_t)colx[e + 12] * 16 + sub];
    a0 += bflo(v0.x) + bflo(v1.x) + bflo(v2.x) + bflo(v3.x);
    a1 += bfhi(v0.x) + bfhi(v1.x) + bfhi(v2.x) + bfhi(v3.x);
    a2 += bflo(v0.y) + bflo(v1.y) + bflo(v2.y) + bflo(v3.y);
    a3 += bfhi(v0.y) + bfhi(v1.y) + bfhi(v2.y) + bfhi(v3.y);
  }
  for (; e < e1; e += 4){
    uint2 v = yb2[(size_t)colx[e] * 16 + sub];
    a0 += bflo(v.x); a1 += bfhi(v.x); a2 += bflo(v.y); a3 += bfhi(v.y);
  }
  #pragma unroll
  for (int off = 16; off < 64; off <<= 1){
    a0 += __shfl_xor(a0, off, 64);
    a1 += __shfl_xor(a1, off, 64);
    a2 += __shfl_xor(a2, off, 64);
    a3 += __shfl_xor(a3, off, 64);
  }
  int deg = e1 - e0;
  float inv = deg > 0 ? 1.f / (float)deg : 0.f;
  float4 zv = ((const float4*)z2)[(size_t)wid * 16 + sub];
  float v0 = a0 * inv + zv.x;
  float v1 = a1 * inv + zv.y;
  float v2 = a2 * inv + zv.z;
  float v3 = a3 * inv + zv.w;
  float mx = fmaxf(fmaxf(v0, v1), fmaxf(v2, v3));
  #pragma unroll
  for (int off = 1; off < 16; off <<= 1) mx = fmaxf(mx, __shfl_xor(mx, off, 64));
  float sm = __expf(v0 - mx) + __expf(v1 - mx) + __expf(v2 - mx) + __expf(v3 - mx);
  #pragma unroll
  for (int off = 1; off < 16; off <<= 1) sm += __shfl_xor(sm, off, 64);
  if (q == 0){
    float ls = __logf(sm);
    float4 o = make_float4((v0 - mx) - ls, (v1 - mx) - ls, (v2 - mx) - ls, (v3 - mx) - ls);
    ((float4*)out)[(size_t)wid * 16 + sub] = o;
  }
}

extern "C" void kernel_launch(void* const* d_in, const int* in_sizes, int n_in,
                              void* d_out, int out_size, void* d_ws, size_t ws_size,
                              hipStream_t stream){
  const float* x    = (const float*)d_in[0];
  const int*   ei   = (const int*)d_in[1];
  const float* w_in = (const float*)d_in[2];
  const float* b_in = (const float*)d_in[3];
  const float* w_l0 = (const float*)d_in[4];
  const float* w_r0 = (const float*)d_in[5];
  const float* b0   = (const float*)d_in[6];
  const float* w_l1 = (const float*)d_in[7];
  const float* w_r1 = (const float*)d_in[8];
  const float* b1   = (const float*)d_in[9];
  const float* w_l2 = (const float*)d_in[10];
  const float* w_r2 = (const float*)d_in[11];
  const float* b2   = (const float*)d_in[12];
  float* out = (float*)d_out;

  char* ws = (char*)d_ws;
  size_t off = 0;
  auto take = [&](size_t bytes) -> char* {
    char* p = ws + off;
    off = (off + bytes + 1023) & ~(size_t)1023;
    return p;
  };
  uint16_t* hb   = (uint16_t*)take((size_t)NN * 128 * 2);   // agg outputs
  uint16_t* resb = (uint16_t*)take((size_t)NN * 128 * 2);   // 0.2*inp
  uint16_t* y0   = (uint16_t*)take((size_t)NN * 128 * 2);   // y (reused each conv)
  uint16_t* z0   = (uint16_t*)take((size_t)NN * 128 * 2);   // z (reused; fp32 z2 at end)
  uint32_t* pairs = (uint32_t*)take((size_t)NE * 4);
  uint16_t* colx  = (uint16_t*)take((size_t)NE * 2);
  int* histG    = (int*)take((size_t)NBIN * ABLK * 4);
  int* binStart = (int*)take((size_t)(NBIN + 1) * 4);
  int* binCur   = (int*)take((size_t)NBIN * 16 * 4);        // line-padded cursors
  int* rowp     = (int*)take((size_t)(NN + 1) * 4);
  uint16_t* BpIn = (uint16_t*)take(128 * 128 * 2);
  uint16_t* Bp0  = (uint16_t*)take(128 * 256 * 2);
  uint16_t* Bp1  = (uint16_t*)take(128 * 256 * 2);
  uint16_t* Bp2  = (uint16_t*)take(128 * 128 * 2);
  uint16_t* y2 = y0;
  float*    z2 = (float*)z0;
  (void)ws_size; (void)in_sizes; (void)n_in; (void)out_size;

  // prep: bucket histogram + weight packs (no cvt — lin0 reads fp32 x directly)
  k_prep<<<B_HIST + B_PIN + B_P0 + B_P1 + B_P2, 256, 0, stream>>>(
      ei, histG, w_in, w_l0, w_r0, w_l1, w_r1, w_l2, w_r2, BpIn, Bp0, Bp1, Bp2);

  // parallel column-sum scan -> binStart + padded cursors
  k_scanG<<<1, 256, 0, stream>>>(histG, binStart, binCur);

  // fused: bucket bin-sort (196 blocks) + lin_in+conv0 GEMM (3125 blocks)
  k_mid<<<B_BIN + NN / 16, 256, 0, stream>>>(ei, binCur, pairs, x, BpIn, b_in, Bp0, b0, resb, y0, z0);

  // per-bucket counting sort -> rowp + colx
  k_csr<<<NBIN, 256, 0, stream>>>(pairs, binStart, rowp, colx);

  // conv0 agg: y0,z0,res -> hb
  agg_mid<<<NN / 4, 256, 0, stream>>>((const uint4*)y0, (const uint4*)z0, (const uint4*)resb,
                                      colx, rowp, (uint4*)hb);
  // conv1 gemm: hb -> y0, z0
  k_gemm<4, 1><<<1024, 256, 0, stream>>>(hb, Bp1, b1, y0, z0, nullptr);

  // conv1 agg: y0,z0,res -> hb
  agg_mid<<<NN / 4, 256, 0, stream>>>((const uint4*)y0, (const uint4*)z0, (const uint4*)resb,
                                      colx, rowp, (uint4*)hb);
  // conv2 gemm: hb -> y2(bf16 64c), z2(fp32 64c)
  k_gemm<2, 2><<<1024, 256, 0, stream>>>(hb, Bp2, b2, y2, nullptr, z2);

  // conv2 agg + log_softmax
  agg_out<<<NN / 4, 256, 0, stream>>>((const uint2*)y2, z2, colx, rowp, out);
}

// Round 11
// 274.715 us; speedup vs baseline: 1.4706x; 1.0536x over previous
//
#include <hip/hip_runtime.h>
#include <stdint.h>

#define NN 50000
#define NE 800000
#define NBIN 196   // dst buckets of 256 nodes (dst >> 8)
#define ABLK 196   // blocks in hist/bin passes
#define EPB 4082   // edges per block: 196*4082 >= NE
#define BCAP 6144  // per-bucket LDS capacity (avg 4096)

typedef __attribute__((ext_vector_type(8))) short short8;
typedef __attribute__((ext_vector_type(4))) float floatx4;

__device__ __forceinline__ uint16_t f2bf(float f){
  union { float f; uint32_t u; } c; c.f = f;
  uint32_t u = c.u + 0x7FFFu + ((c.u >> 16) & 1u);
  return (uint16_t)(u >> 16);
}
__device__ __forceinline__ float bflo(uint32_t v){
  union { uint32_t u; float f; } c; c.u = v << 16; return c.f;
}
__device__ __forceinline__ float bfhi(uint32_t v){
  union { uint32_t u; float f; } c; c.u = v & 0xFFFF0000u; return c.f;
}

// ---------------- prep: bucket histogram + weight packs ----------------
#define B_HIST ABLK
#define B_PIN 64
#define B_P0  128
#define B_P1  128
#define B_P2  64

__device__ __forceinline__ void pack_one(int idx, const float* __restrict__ wl,
                                         const float* __restrict__ wr,
                                         uint16_t* __restrict__ bp,
                                         int ncolL, int ncolR, int NT){
  int j = idx & 7, lane = (idx >> 3) & 63, rest = idx >> 9;
  int nt = rest % NT, kt = rest / NT;
  int k = kt * 32 + ((lane >> 4) << 3) + j;
  int n = nt * 16 + (lane & 15);
  float v = (n < ncolL) ? wl[k * ncolL + n] : wr[k * ncolR + (n - ncolL)];
  bp[idx] = f2bf(v);
}

__global__ __launch_bounds__(256) void k_prep(const int* __restrict__ ei, int* __restrict__ histG,
                                              const float* __restrict__ w_in,
                                              const float* __restrict__ w_l0, const float* __restrict__ w_r0,
                                              const float* __restrict__ w_l1, const float* __restrict__ w_r1,
                                              const float* __restrict__ w_l2, const float* __restrict__ w_r2,
                                              uint16_t* __restrict__ bpIn, uint16_t* __restrict__ bp0,
                                              uint16_t* __restrict__ bp1, uint16_t* __restrict__ bp2){
  __shared__ int hsh[NBIN];
  int b = blockIdx.x;
  if (b < B_HIST){
    for (int i = threadIdx.x; i < NBIN; i += 256) hsh[i] = 0;
    __syncthreads();
    int base = b * EPB;
    for (int k = threadIdx.x; k < EPB; k += 256){
      int e = base + k;
      if (e < NE) atomicAdd(&hsh[ei[NE + e] >> 8], 1);
    }
    __syncthreads();
    for (int i = threadIdx.x; i < NBIN; i += 256) histG[b * NBIN + i] = hsh[i];
    return;
  }
  b -= B_HIST;
  if (b < B_PIN){ pack_one(b * 256 + threadIdx.x, w_in, w_in, bpIn, 128, 0, 8); return; }
  b -= B_PIN;
  if (b < B_P0){ pack_one(b * 256 + threadIdx.x, w_l0, w_r0, bp0, 128, 128, 16); return; }
  b -= B_P0;
  if (b < B_P1){ pack_one(b * 256 + threadIdx.x, w_l1, w_r1, bp1, 128, 128, 16); return; }
  b -= B_P1;
  pack_one(b * 256 + threadIdx.x, w_l2, w_r2, bp2, 64, 64, 8);
}

// ---------------- scan S1: one block per bin; within-column exclusive prefixes (in-place) ----------------
__global__ __launch_bounds__(256) void k_scanS1(int* __restrict__ histG, int* __restrict__ colTot){
  __shared__ int s[256];
  int t = blockIdx.x;            // bin
  int b = threadIdx.x;           // source block
  int v = (b < ABLK) ? histG[b * NBIN + t] : 0;
  s[b] = v;
  __syncthreads();
  #pragma unroll
  for (int off = 1; off < 256; off <<= 1){
    int u = (b >= off) ? s[b - off] : 0;
    __syncthreads();
    s[b] += u;
    __syncthreads();
  }
  if (b < ABLK) histG[b * NBIN + t] = s[b] - v;   // exclusive prefix within column
  if (b == ABLK - 1) colTot[t] = s[b];
}

// ---------------- scan S2: bin-level scan -> binStart ----------------
__global__ __launch_bounds__(256) void k_scanS2(const int* __restrict__ colTot, int* __restrict__ binStart){
  __shared__ int s[256];
  int t = threadIdx.x;
  int tot = (t < NBIN) ? colTot[t] : 0;
  s[t] = tot;
  __syncthreads();
  #pragma unroll
  for (int off = 1; off < 256; off <<= 1){
    int u = (t >= off) ? s[t - off] : 0;
    __syncthreads();
    s[t] += u;
    __syncthreads();
  }
  if (t < NBIN) binStart[t] = s[t] - tot;
  if (t == 0) binStart[NBIN] = NE;
}

// ---------------- k_mid: fused [bucket bin-sort (196 blocks)] + [lin_in+conv0 GEMM (3125 blocks)] ----------------
#define B_BIN 196
#define SMSZ 20488   // bin branch: 4*NBIN*4 + 256*4 + EPB*4

__global__ __launch_bounds__(256) void k_mid(const int* __restrict__ ei, const int* __restrict__ histG,
                                             const int* __restrict__ binStart,
                                             uint32_t* __restrict__ pairs,
                                             const float* __restrict__ x,
                                             const uint16_t* __restrict__ BpIn, const float* __restrict__ b_in,
                                             const uint16_t* __restrict__ Bp0, const float* __restrict__ b0,
                                             uint16_t* __restrict__ resb, uint16_t* __restrict__ y0,
                                             uint16_t* __restrict__ z0){
  __shared__ __align__(16) char smraw[SMSZ];
  int t = threadIdx.x;
  if (blockIdx.x < B_BIN){
    // ---- bucket bin-sort (offsets fully precomputed; zero global atomics) ----
    int* h   = (int*)smraw;
    int* loc = h + NBIN;
    int* cur = loc + NBIN;
    int* gof = cur + NBIN;
    int* sc  = gof + NBIN;
    uint32_t* st = (uint32_t*)(sc + 256);
    int base = blockIdx.x * EPB;
    for (int i = t; i < NBIN; i += 256) h[i] = 0;
    __syncthreads();
    for (int k = t; k < EPB; k += 256){
      int e = base + k;
      if (e < NE) atomicAdd(&h[ei[NE + e] >> 8], 1);
    }
    __syncthreads();
    int cv = (t < NBIN) ? h[t] : 0;
    sc[t] = cv;
    __syncthreads();
    #pragma unroll
    for (int off = 1; off < 256; off <<= 1){
      int u = (t >= off) ? sc[t - off] : 0;
      __syncthreads();
      sc[t] += u;
      __syncthreads();
    }
    if (t < NBIN){
      int excl = sc[t] - cv;
      loc[t] = excl;
      cur[t] = excl;
      gof[t] = binStart[t] + histG[blockIdx.x * NBIN + t];
    }
    __syncthreads();
    for (int k = t; k < EPB; k += 256){
      int e = base + k;
      if (e < NE){
        int d = ei[NE + e];
        int s0 = ei[e];
        int pos = atomicAdd(&cur[d >> 8], 1);
        st[pos] = (uint32_t)s0 | ((uint32_t)d << 16);
      }
    }
    __syncthreads();
    int cnt = min(EPB, NE - base);
    for (int k = t; k < cnt; k += 256){
      uint32_t v = st[k];
      int bin = (int)(v >> 24);
      pairs[gof[bin] + (k - loc[bin])] = v;
    }
    return;
  }
  // ---- lin_in + conv0 GEMM (reads fp32 x directly) ----
  uint16_t* ash = (uint16_t*)smraw;   // 16 x 128, stride 136
  int lane = t & 63, wave = t >> 6;
  short8 bIn[4][2], bC0[4][4];
  #pragma unroll
  for (int kt = 0; kt < 4; ++kt){
    #pragma unroll
    for (int n = 0; n < 2; ++n)
      bIn[kt][n] = *(const short8*)(BpIn + (size_t)((kt * 8 + wave * 2 + n) * 64 + lane) * 8);
    #pragma unroll
    for (int n = 0; n < 4; ++n)
      bC0[kt][n] = *(const short8*)(Bp0 + (size_t)((kt * 16 + wave * 4 + n) * 64 + lane) * 8);
  }
  int m = lane & 15, quad = lane >> 4;
  int r0 = (blockIdx.x - B_BIN) * 16;
  const float* xrow = x + (size_t)(r0 + m) * 128 + quad * 8;
  short8 af[4];
  #pragma unroll
  for (int kt = 0; kt < 4; ++kt){
    float4 p = *(const float4*)(xrow + kt * 32);
    float4 q2 = *(const float4*)(xrow + kt * 32 + 4);
    short8 a;
    a[0] = (short)f2bf(p.x);  a[1] = (short)f2bf(p.y);
    a[2] = (short)f2bf(p.z);  a[3] = (short)f2bf(p.w);
    a[4] = (short)f2bf(q2.x); a[5] = (short)f2bf(q2.y);
    a[6] = (short)f2bf(q2.z); a[7] = (short)f2bf(q2.w);
    af[kt] = a;
  }
  floatx4 accH[2];
  #pragma unroll
  for (int n = 0; n < 2; ++n) accH[n] = (floatx4){0.f, 0.f, 0.f, 0.f};
  #pragma unroll
  for (int kt = 0; kt < 4; ++kt)
    #pragma unroll
    for (int n = 0; n < 2; ++n)
      accH[n] = __builtin_amdgcn_mfma_f32_16x16x32_bf16(af[kt], bIn[kt][n], accH[n], 0, 0, 0);
  int rbase = r0 + quad * 4;
  #pragma unroll
  for (int n = 0; n < 2; ++n){
    int c = (wave * 2 + n) * 16 + m;
    float bi = b_in[c];
    #pragma unroll
    for (int i = 0; i < 4; ++i){
      float hh = accH[n][i] + bi;
      int row = rbase + i;
      resb[(size_t)row * 128 + c] = f2bf(0.2f * hh);
      ash[(quad * 4 + i) * 136 + c] = f2bf(fmaxf(hh, 0.f));
    }
  }
  __syncthreads();
  short8 af2[4];
  #pragma unroll
  for (int kt = 0; kt < 4; ++kt)
    af2[kt] = *(const short8*)&ash[m * 136 + quad * 8 + kt * 32];
  floatx4 acc[4];
  #pragma unroll
  for (int n = 0; n < 4; ++n) acc[n] = (floatx4){0.f, 0.f, 0.f, 0.f};
  #pragma unroll
  for (int kt = 0; kt < 4; ++kt)
    #pragma unroll
    for (int n = 0; n < 4; ++n)
      acc[n] = __builtin_amdgcn_mfma_f32_16x16x32_bf16(af2[kt], bC0[kt][n], acc[n], 0, 0, 0);
  #pragma unroll
  for (int n = 0; n < 4; ++n){
    int c = (wave * 4 + n) * 16 + m;
    #pragma unroll
    for (int i = 0; i < 4; ++i){
      float v = acc[n][i];
      int row = rbase + i;
      if (c < 128) y0[(size_t)row * 128 + c] = f2bf(v);
      else         z0[(size_t)row * 128 + (c - 128)] = f2bf(v + b0[c - 128]);
    }
  }
}

// ---------------- pass B: per-bucket counting sort -> rowp + colx(u16) ----------------
__global__ __launch_bounds__(256) void k_csr(const uint32_t* __restrict__ pairs, const int* __restrict__ binStart,
                                             int* __restrict__ rowp, uint16_t* __restrict__ colx){
  __shared__ uint32_t pl[BCAP];
  __shared__ uint16_t stg[BCAP];
  __shared__ int h[256], sc[256];
  int i = blockIdx.x, t = threadIdx.x;
  int p0 = binStart[i], p1 = binStart[i + 1];
  int cnt = min(p1 - p0, BCAP);
  for (int k = t; k < cnt; k += 256) pl[k] = pairs[p0 + k];
  h[t] = 0;
  __syncthreads();
  for (int k = t; k < cnt; k += 256) atomicAdd(&h[(pl[k] >> 16) & 255], 1);
  __syncthreads();
  int cv = h[t];
  sc[t] = cv;
  __syncthreads();
  #pragma unroll
  for (int off = 1; off < 256; off <<= 1){
    int u = (t >= off) ? sc[t - off] : 0;
    __syncthreads();
    sc[t] += u;
    __syncthreads();
  }
  int excl = sc[t] - cv;
  int n0 = i << 8;
  int nc = min(256, NN - n0);
  if (t < nc) rowp[n0 + t] = p0 + excl;
  if (i == NBIN - 1 && t == 0) rowp[NN] = NE;
  h[t] = excl;   // becomes cursor
  __syncthreads();
  for (int k = t; k < cnt; k += 256){
    uint32_t v = pl[k];
    int pos = atomicAdd(&h[(v >> 16) & 255], 1);
    stg[pos] = (uint16_t)(v & 0xFFFFu);
  }
  __syncthreads();
  for (int k = t; k < cnt; k += 256) colx[p0 + k] = stg[k];
}

// ------------- GEMM: A[N,128]bf16 @ Bp[128, NCOL] -> epilogue -------------
template<int NTW, int MODE>
__global__ __launch_bounds__(256) void k_gemm(const uint16_t* __restrict__ A, const uint16_t* __restrict__ Bp,
                                              const float* __restrict__ bias,
                                              uint16_t* __restrict__ o0, uint16_t* __restrict__ o1,
                                              float* __restrict__ o2){
  const int NTT = 4 * NTW;
  int lane = threadIdx.x & 63;
  int wave = threadIdx.x >> 6;
  short8 bfrag[4][NTW];
  #pragma unroll
  for (int kt = 0; kt < 4; ++kt)
    #pragma unroll
    for (int n = 0; n < NTW; ++n)
      bfrag[kt][n] = *(const short8*)(Bp + (size_t)((kt * NTT + wave * NTW + n) * 64 + lane) * 8);

  int m = lane & 15, quad = lane >> 4;
  const int nrt = NN / 16;
  for (int rt = blockIdx.x; rt < nrt; rt += gridDim.x){
    int r0 = rt * 16;
    const uint16_t* arow = A + (size_t)(r0 + m) * 128 + quad * 8;
    short8 af[4];
    #pragma unroll
    for (int kt = 0; kt < 4; ++kt) af[kt] = *(const short8*)(arow + kt * 32);
    floatx4 acc[NTW];
    #pragma unroll
    for (int n = 0; n < NTW; ++n) acc[n] = (floatx4){0.f, 0.f, 0.f, 0.f};
    #pragma unroll
    for (int kt = 0; kt < 4; ++kt)
      #pragma unroll
      for (int n = 0; n < NTW; ++n)
        acc[n] = __builtin_amdgcn_mfma_f32_16x16x32_bf16(af[kt], bfrag[kt][n], acc[n], 0, 0, 0);

    int rbase = r0 + quad * 4;
    #pragma unroll
    for (int n = 0; n < NTW; ++n){
      int c = (wave * NTW + n) * 16 + m;
      #pragma unroll
      for (int i = 0; i < 4; ++i){
        float v = acc[n][i];
        int row = rbase + i;
        if (MODE == 1){
          if (c < 128) o0[(size_t)row * 128 + c] = f2bf(v);
          else         o1[(size_t)row * 128 + (c - 128)] = f2bf(v + bias[c - 128]);
        } else {
          if (c < 64) o0[(size_t)row * 64 + c] = f2bf(v);
          else        o2[(size_t)row * 64 + (c - 64)] = v + bias[c - 64];
        }
      }
    }
  }
}

// ------------- aggregation: one wave per node; quarter-wave (16 lanes x uint4) per edge -------------
__global__ __launch_bounds__(256) void agg_mid(const uint4* __restrict__ yb, const uint4* __restrict__ zb,
                                               const uint4* __restrict__ resb,
                                               const uint16_t* __restrict__ colx, const int* __restrict__ rowp,
                                               uint4* __restrict__ hb_out){
  int wid = blockIdx.x * 4 + (threadIdx.x >> 6);
  if (wid >= NN) return;
  int lane = threadIdx.x & 63;
  int q = lane >> 4, sub = lane & 15;
  int e0 = rowp[wid], e1 = rowp[wid + 1];
  float a0 = 0.f, a1 = 0.f, a2 = 0.f, a3 = 0.f, a4 = 0.f, a5 = 0.f, a6 = 0.f, a7 = 0.f;
  int e = e0 + q;
  for (; e + 12 < e1; e += 16){
    uint4 v0 = yb[(size_t)colx[e]      * 16 + sub];
    uint4 v1 = yb[(size_t)colx[e + 4]  * 16 + sub];
    uint4 v2 = yb[(size_t)colx[e + 8]  * 16 + sub];
    uint4 v3 = yb[(size_t)colx[e + 12] * 16 + sub];
    a0 += bflo(v0.x) + bflo(v1.x) + bflo(v2.x) + bflo(v3.x);
    a1 += bfhi(v0.x) + bfhi(v1.x) + bfhi(v2.x) + bfhi(v3.x);
    a2 += bflo(v0.y) + bflo(v1.y) + bflo(v2.y) + bflo(v3.y);
    a3 += bfhi(v0.y) + bfhi(v1.y) + bfhi(v2.y) + bfhi(v3.y);
    a4 += bflo(v0.z) + bflo(v1.z) + bflo(v2.z) + bflo(v3.z);
    a5 += bfhi(v0.z) + bfhi(v1.z) + bfhi(v2.z) + bfhi(v3.z);
    a6 += bflo(v0.w) + bflo(v1.w) + bflo(v2.w) + bflo(v3.w);
    a7 += bfhi(v0.w) + bfhi(v1.w) + bfhi(v2.w) + bfhi(v3.w);
  }
  for (; e < e1; e += 4){
    uint4 v = yb[(size_t)colx[e] * 16 + sub];
    a0 += bflo(v.x); a1 += bfhi(v.x); a2 += bflo(v.y); a3 += bfhi(v.y);
    a4 += bflo(v.z); a5 += bfhi(v.z); a6 += bflo(v.w); a7 += bfhi(v.w);
  }
  #pragma unroll
  for (int off = 16; off < 64; off <<= 1){
    a0 += __shfl_xor(a0, off, 64);
    a1 += __shfl_xor(a1, off, 64);
    a2 += __shfl_xor(a2, off, 64);
    a3 += __shfl_xor(a3, off, 64);
    a4 += __shfl_xor(a4, off, 64);
    a5 += __shfl_xor(a5, off, 64);
    a6 += __shfl_xor(a6, off, 64);
    a7 += __shfl_xor(a7, off, 64);
  }
  int deg = e1 - e0;
  float inv = deg > 0 ? 1.f / (float)deg : 0.f;
  if (q == 0){
    uint4 zv = zb[(size_t)wid * 16 + sub];
    uint4 rv = resb[(size_t)wid * 16 + sub];
    float w0 = fmaxf(a0 * inv + bflo(zv.x), 0.f) + bflo(rv.x);
    float w1 = fmaxf(a1 * inv + bfhi(zv.x), 0.f) + bfhi(rv.x);
    float w2 = fmaxf(a2 * inv + bflo(zv.y), 0.f) + bflo(rv.y);
    float w3 = fmaxf(a3 * inv + bfhi(zv.y), 0.f) + bfhi(rv.y);
    float w4 = fmaxf(a4 * inv + bflo(zv.z), 0.f) + bflo(rv.z);
    float w5 = fmaxf(a5 * inv + bfhi(zv.z), 0.f) + bfhi(rv.z);
    float w6 = fmaxf(a6 * inv + bflo(zv.w), 0.f) + bflo(rv.w);
    float w7 = fmaxf(a7 * inv + bfhi(zv.w), 0.f) + bfhi(rv.w);
    uint4 o;
    o.x = (uint32_t)f2bf(w0) | ((uint32_t)f2bf(w1) << 16);
    o.y = (uint32_t)f2bf(w2) | ((uint32_t)f2bf(w3) << 16);
    o.z = (uint32_t)f2bf(w4) | ((uint32_t)f2bf(w5) << 16);
    o.w = (uint32_t)f2bf(w6) | ((uint32_t)f2bf(w7) << 16);
    hb_out[(size_t)wid * 16 + sub] = o;
  }
}

// ------------- final aggregation + log_softmax (quarter-wave, uint2 loads, 4 dims/lane) -------------
__global__ __launch_bounds__(256) void agg_out(const uint2* __restrict__ yb2, const float* __restrict__ z2,
                                               const uint16_t* __restrict__ colx, const int* __restrict__ rowp,
                                               float* __restrict__ out){
  int wid = blockIdx.x * 4 + (threadIdx.x >> 6);
  if (wid >= NN) return;
  int lane = threadIdx.x & 63;
  int q = lane >> 4, sub = lane & 15;
  int e0 = rowp[wid], e1 = rowp[wid + 1];
  float a0 = 0.f, a1 = 0.f, a2 = 0.f, a3 = 0.f;
  int e = e0 + q;
  for (; e + 12 < e1; e += 16){
    uint2 v0 = yb2[(size_t)colx[e]      * 16 + sub];
    uint2 v1 = yb2[(size_t)colx[e + 4]  * 16 + sub];
    uint2 v2 = yb2[(size_t)colx[e + 8]  * 16 + sub];
    uint2 v3 = yb2[(size_t)colx[e + 12] * 16 + sub];
    a0 += bflo(v0.x) + bflo(v1.x) + bflo(v2.x) + bflo(v3.x);
    a1 += bfhi(v0.x) + bfhi(v1.x) + bfhi(v2.x) + bfhi(v3.x);
    a2 += bflo(v0.y) + bflo(v1.y) + bflo(v2.y) + bflo(v3.y);
    a3 += bfhi(v0.y) + bfhi(v1.y) + bfhi(v2.y) + bfhi(v3.y);
  }
  for (; e < e1; e += 4){
    uint2 v = yb2[(size_t)colx[e] * 16 + sub];
    a0 += bflo(v.x); a1 += bfhi(v.x); a2 += bflo(v.y); a3 += bfhi(v.y);
  }
  #pragma unroll
  for (int off = 16; off < 64; off <<= 1){
    a0 += __shfl_xor(a0, off, 64);
    a1 += __shfl_xor(a1, off, 64);
    a2 += __shfl_xor(a2, off, 64);
    a3 += __shfl_xor(a3, off, 64);
  }
  int deg = e1 - e0;
  float inv = deg > 0 ? 1.f / (float)deg : 0.f;
  float4 zv = ((const float4*)z2)[(size_t)wid * 16 + sub];
  float v0 = a0 * inv + zv.x;
  float v1 = a1 * inv + zv.y;
  float v2 = a2 * inv + zv.z;
  float v3 = a3 * inv + zv.w;
  float mx = fmaxf(fmaxf(v0, v1), fmaxf(v2, v3));
  #pragma unroll
  for (int off = 1; off < 16; off <<= 1) mx = fmaxf(mx, __shfl_xor(mx, off, 64));
  float sm = __expf(v0 - mx) + __expf(v1 - mx) + __expf(v2 - mx) + __expf(v3 - mx);
  #pragma unroll
  for (int off = 1; off < 16; off <<= 1) sm += __shfl_xor(sm, off, 64);
  if (q == 0){
    float ls = __logf(sm);
    float4 o = make_float4((v0 - mx) - ls, (v1 - mx) - ls, (v2 - mx) - ls, (v3 - mx) - ls);
    ((float4*)out)[(size_t)wid * 16 + sub] = o;
  }
}

extern "C" void kernel_launch(void* const* d_in, const int* in_sizes, int n_in,
                              void* d_out, int out_size, void* d_ws, size_t ws_size,
                              hipStream_t stream){
  const float* x    = (const float*)d_in[0];
  const int*   ei   = (const int*)d_in[1];
  const float* w_in = (const float*)d_in[2];
  const float* b_in = (const float*)d_in[3];
  const float* w_l0 = (const float*)d_in[4];
  const float* w_r0 = (const float*)d_in[5];
  const float* b0   = (const float*)d_in[6];
  const float* w_l1 = (const float*)d_in[7];
  const float* w_r1 = (const float*)d_in[8];
  const float* b1   = (const float*)d_in[9];
  const float* w_l2 = (const float*)d_in[10];
  const float* w_r2 = (const float*)d_in[11];
  const float* b2   = (const float*)d_in[12];
  float* out = (float*)d_out;

  char* ws = (char*)d_ws;
  size_t off = 0;
  auto take = [&](size_t bytes) -> char* {
    char* p = ws + off;
    off = (off + bytes + 1023) & ~(size_t)1023;
    return p;
  };
  uint16_t* hb   = (uint16_t*)take((size_t)NN * 128 * 2);   // agg outputs
  uint16_t* resb = (uint16_t*)take((size_t)NN * 128 * 2);   // 0.2*inp
  uint16_t* y0   = (uint16_t*)take((size_t)NN * 128 * 2);   // y (reused each conv)
  uint16_t* z0   = (uint16_t*)take((size_t)NN * 128 * 2);   // z (reused; fp32 z2 at end)
  uint32_t* pairs = (uint32_t*)take((size_t)NE * 4);
  uint16_t* colx  = (uint16_t*)take((size_t)NE * 2);
  int* histG    = (int*)take((size_t)NBIN * ABLK * 4);
  int* colTot   = (int*)take((size_t)NBIN * 4);
  int* binStart = (int*)take((size_t)(NBIN + 1) * 4);
  int* rowp     = (int*)take((size_t)(NN + 1) * 4);
  uint16_t* BpIn = (uint16_t*)take(128 * 128 * 2);
  uint16_t* Bp0  = (uint16_t*)take(128 * 256 * 2);
  uint16_t* Bp1  = (uint16_t*)take(128 * 256 * 2);
  uint16_t* Bp2  = (uint16_t*)take(128 * 128 * 2);
  uint16_t* y2 = y0;
  float*    z2 = (float*)z0;
  (void)ws_size; (void)in_sizes; (void)n_in; (void)out_size;

  // prep: bucket histogram + weight packs
  k_prep<<<B_HIST + B_PIN + B_P0 + B_P1 + B_P2, 256, 0, stream>>>(
      ei, histG, w_in, w_l0, w_r0, w_l1, w_r1, w_l2, w_r2, BpIn, Bp0, Bp1, Bp2);

  // parallel offset computation (no atomics anywhere downstream)
  k_scanS1<<<NBIN, 256, 0, stream>>>(histG, colTot);
  k_scanS2<<<1, 256, 0, stream>>>(colTot, binStart);

  // fused: bucket bin-sort (196 blocks) + lin_in+conv0 GEMM (3125 blocks)
  k_mid<<<B_BIN + NN / 16, 256, 0, stream>>>(ei, histG, binStart, pairs, x,
                                             BpIn, b_in, Bp0, b0, resb, y0, z0);

  // per-bucket counting sort -> rowp + colx
  k_csr<<<NBIN, 256, 0, stream>>>(pairs, binStart, rowp, colx);

  // conv0 agg: y0,z0,res -> hb
  agg_mid<<<NN / 4, 256, 0, stream>>>((const uint4*)y0, (const uint4*)z0, (const uint4*)resb,
                                      colx, rowp, (uint4*)hb);
  // conv1 gemm: hb -> y0, z0
  k_gemm<4, 1><<<1024, 256, 0, stream>>>(hb, Bp1, b1, y0, z0, nullptr);

  // conv1 agg: y0,z0,res -> hb
  agg_mid<<<NN / 4, 256, 0, stream>>>((const uint4*)y0, (const uint4*)z0, (const uint4*)resb,
                                      colx, rowp, (uint4*)hb);
  // conv2 gemm: hb -> y2(bf16 64c), z2(fp32 64c)
  k_gemm<2, 2><<<1024, 256, 0, stream>>>(hb, Bp2, b2, y2, nullptr, z2);

  // conv2 agg + log_softmax
  agg_out<<<NN / 4, 256, 0, stream>>>((const uint2*)y2, z2, colx, rowp, out);
}